// Round 12
// baseline (1197.667 us; speedup 1.0000x reference)
//
#include <hip/hip_runtime.h>
#include <stdint.h>

// CGCNN forward, round 12: edge_mm occupancy 2->3 blocks/CU without spill.
//  Round-9 re-analysis: its traffic blowup was SPILL (symmetric FETCH/WRITE
//  growth), not concurrency-induced L2 thrash; Ptop/Pmid are L3-resident.
//  Epilogue re-batched in two groups of 8 rg (live gather regs 96->48) so the
//  kernel fits launch_bounds(256,3) (~170-reg budget). Single-variable A/B vs
//  round 11. Everything else unchanged.
// Biases before BN cancel exactly -> skipped.

#define N_NODES 50000
#define M_EDGES 800000
#define FV 92
#define FE 41
#define EMB 64
#define NL 3
#define EPS 1e-5f
#define NPART 8

typedef unsigned short u16;
typedef unsigned int u32;
typedef __attribute__((ext_vector_type(8))) short bf16x8;
typedef __attribute__((ext_vector_type(16))) float f32x16;

__device__ __forceinline__ float bf2f(u16 u) {
  return __uint_as_float(((u32)u) << 16);
}
__device__ __forceinline__ u16 f2bf(float f) {
  u32 x = __float_as_uint(f);
  return (u16)((x + 0x7fffu + ((x >> 16) & 1u)) >> 16);
}
__device__ __forceinline__ float sigmoidf_(float x) { return 1.0f / (1.0f + __expf(-x)); }
__device__ __forceinline__ float softplusf_(float x) {
  return fmaxf(x, 0.f) + __logf(1.f + __expf(-fabsf(x)));
}
__device__ __forceinline__ float siluf_(float x) { return x * sigmoidf_(x); }

// ---------------- preprocessing ----------------

__global__ void zero_kernel(int* nexts, float* stats, int nInts, int nFloats) {
  int i = blockIdx.x * 256 + threadIdx.x;
  if (i < nInts) nexts[i] = 0;
  if (i < nFloats) stats[i] = 0.f;
}

__global__ void hist_kernel(const int* dst, int* hist) {
  int e = blockIdx.x * 256 + threadIdx.x;
  if (e < M_EDGES) atomicAdd(&hist[dst[e]], 1);
}

__global__ void scanA_kernel(const int* hist, int* bsum) {
  int tid = threadIdx.x;
  int i = blockIdx.x * 256 + tid;
  int x = (i < N_NODES) ? hist[i] : 0;
  #pragma unroll
  for (int o = 32; o > 0; o >>= 1) x += __shfl_xor(x, o);
  __shared__ int wsm[4];
  if ((tid & 63) == 0) wsm[tid >> 6] = x;
  __syncthreads();
  if (tid == 0) bsum[blockIdx.x] = wsm[0] + wsm[1] + wsm[2] + wsm[3];
}

__global__ void scanB_kernel(const int* bsum, int* boffs, int* row_ptr) {
  int tid = threadIdx.x;
  int lane = tid & 63, wid = tid >> 6;
  int x = (tid < 196) ? bsum[tid] : 0;
  int v = x;
  #pragma unroll
  for (int o = 1; o < 64; o <<= 1) {
    int nv = __shfl_up(v, o);
    if (lane >= o) v += nv;
  }
  __shared__ int wsm[4];
  if (lane == 63) wsm[wid] = v;
  __syncthreads();
  int add = 0;
  for (int wq = 0; wq < wid; wq++) add += wsm[wq];
  if (tid < 196) boffs[tid] = v + add - x;  // exclusive
  if (tid == 0) row_ptr[N_NODES] = M_EDGES;
}

__global__ void scanC_kernel(const int* hist, const int* boffs, int* row_ptr, int* nexts) {
  int tid = threadIdx.x;
  int i = blockIdx.x * 256 + tid;
  int lane = tid & 63, wid = tid >> 6;
  int x = (i < N_NODES) ? hist[i] : 0;
  int v = x;
  #pragma unroll
  for (int o = 1; o < 64; o <<= 1) {
    int nv = __shfl_up(v, o);
    if (lane >= o) v += nv;
  }
  __shared__ int wsm[4];
  if (lane == 63) wsm[wid] = v;
  __syncthreads();
  int add = boffs[blockIdx.x];
  for (int wq = 0; wq < wid; wq++) add += wsm[wq];
  int excl = v - x + add;
  if (i < N_NODES) { row_ptr[i] = excl; nexts[i] = excl; }
}

__global__ void scatter_kernel(const int* src, const int* dst, int* nexts, int* eid_s) {
  int e = blockIdx.x * 256 + threadIdx.x;
  if (e < M_EDGES) {
    int p = atomicAdd(&nexts[dst[e]], 1);
    eid_s[p] = e;
  }
}

// gather-direction permute (coalesced writes, zero-padded 48 cols) +
// materialize src_s/dst_s (random L2 reads, coalesced writes)
__global__ void permute_ef_kernel(const float* ef, const int* eid_s,
                                  const int* src, const int* dst,
                                  u16* ef_s, int* src_s, int* dst_s) {
  int tid = threadIdx.x;
  u32 p = blockIdx.x * 32 + (tid >> 3);  // 25000 blocks * 32 rows = M
  int q = tid & 7;
  int e = eid_s[p];
  if (q == 0) { src_s[p] = src[e]; dst_s[p] = dst[e]; }
  const float* base = ef + (size_t)e * 41;
  u32* orow = (u32*)ef_s + (size_t)p * 24 + q * 3;
  #pragma unroll
  for (int i = 0; i < 3; i++) {
    int k = q * 6 + i * 2;
    float lo = (k < 41) ? base[k] : 0.f;
    float hi = (k + 1 < 41) ? base[k + 1] : 0.f;
    orow[i] = (u32)f2bf(lo) | ((u32)f2bf(hi) << 16);
  }
}

// ---------------- embedding (matmul + fused column stats, 8-slot partials) ---

__global__ void emb_mm_kernel(const float* nf, const float* Wemb, float* y0,
                              float* s1, float* s2) {
  __shared__ float Wl[FV][EMB];          // 23.5 KB
  __shared__ float ps[16][64], pq2[16][64];  // 8 KB
  int tid = threadIdx.x;
  for (int idx = tid; idx < FV * EMB; idx += 256) Wl[idx >> 6][idx & 63] = Wemb[idx];
  __syncthreads();
  int t = blockIdx.x * 256 + tid;  // N*16
  int n = t >> 4, q = t & 15;
  const float* row = nf + n * FV;
  float a0 = 0, a1 = 0, a2 = 0, a3 = 0;
  #pragma unroll 4
  for (int k = 0; k < FV; k++) {
    float x = row[k];
    float4 w = *(const float4*)&Wl[k][q * 4];
    a0 = fmaf(x, w.x, a0); a1 = fmaf(x, w.y, a1);
    a2 = fmaf(x, w.z, a2); a3 = fmaf(x, w.w, a3);
  }
  float4 r; r.x = a0; r.y = a1; r.z = a2; r.w = a3;
  *(float4*)&y0[n * EMB + q * 4] = r;
  int nl = tid >> 4, q4 = (tid & 15) * 4;
  ps[nl][q4] = a0; ps[nl][q4 + 1] = a1; ps[nl][q4 + 2] = a2; ps[nl][q4 + 3] = a3;
  pq2[nl][q4] = a0 * a0; pq2[nl][q4 + 1] = a1 * a1;
  pq2[nl][q4 + 2] = a2 * a2; pq2[nl][q4 + 3] = a3 * a3;
  __syncthreads();
  if (tid < 64) {
    float s = 0, ss = 0;
    #pragma unroll
    for (int g = 0; g < 16; g++) { s += ps[g][tid]; ss += pq2[g][tid]; }
    int part = blockIdx.x & (NPART - 1);
    atomicAdd(&s1[part * 64 + tid], s);
    atomicAdd(&s2[part * 64 + tid], ss);
  }
}

// ---------------- fused BN-finalize + v activation + P tables (MFMA) --------
// mode 0: v = silu(bn(X)); mode 1: v = softplus(bn(X)+v). Then P = v @ W
// halves via mfma_32x32x16_bf16. 64 nodes/block, grid 782 (tail guarded).
// vls: bf16 v rows XOR-swizzled (u16 idx = c ^ ((row&7)<<3)) -> conflict-free
// ds_read_b128 A-frags. WbF: B-frags (lane l: col=l&31, k=ks*16+(l>>5)*8+j),
// interleaved cols ic=cg*32+l31 -> feature ic>>1, table-half ic&1.
// P write: u16 at [node*128 + cg*32 + l31] (64 B contiguous per half-wave).

__global__ __launch_bounds__(256) void finv_ptab_kernel(
    const float* __restrict__ X, float* __restrict__ vio,
    const float* s1, const float* s2, const float* g, const float* be,
    const float* __restrict__ Wm_l, const float* __restrict__ Ws_l,
    u16* __restrict__ Ptop, u16* __restrict__ Pmid, float minv, int mode) {
  __shared__ u16 vls[64 * 64];   // 8 KB
  __shared__ u16 WbF[16384];     // 32 KB: [mat][cg][ks][lane]*8
  __shared__ float aS[64], cS[64];
  int tid = threadIdx.x;
  if (tid < 64) {
    float sA = 0, sB = 0;
    #pragma unroll
    for (int p = 0; p < NPART; p++) { sA += s1[p * 64 + tid]; sB += s2[p * 64 + tid]; }
    float mean = sA * minv;
    float var = sB * minv - mean * mean;
    float av = g[tid] * rsqrtf(var + EPS);
    aS[tid] = av; cS[tid] = be[tid] - mean * av;
  }
  __syncthreads();
  int nb = blockIdx.x * 64;
  #pragma unroll
  for (int it = 0; it < 16; it++) {
    int idx = it * 256 + tid;
    int nl = idx >> 6, c = idx & 63;
    int n = nb + nl;
    float vn = 0.f;
    if (n < N_NODES) {
      size_t gi = (size_t)n * 64 + c;
      float z = fmaf(aS[c], X[gi], cS[c]);
      vn = mode ? softplusf_(z + vio[gi]) : siluf_(z);
      vio[gi] = vn;
    }
    vls[nl * 64 + (c ^ ((nl & 7) << 3))] = f2bf(vn);
  }
  // stage W as B-frags for both table halves (mat 0: W rows 0..63 -> Ptop;
  // mat 1: rows 64..127 -> Pmid)
  for (int t = tid; t < 16384; t += 256) {
    int slot = t >> 3, j = t & 7;
    int mat = slot >> 10;
    int rem = slot & 1023;
    int cg = rem >> 8;
    int rem2 = rem & 255;
    int ks = rem2 >> 6, ln = rem2 & 63;
    int ic = cg * 32 + (ln & 31);
    int feat = ic >> 1, scr = ic & 1;
    int k = ks * 16 + ((ln >> 5) << 3) + j;
    int wrow = mat * 64 + k;
    float val = scr ? Ws_l[wrow * 64 + feat] : Wm_l[wrow * 64 + feat];
    WbF[t] = f2bf(val);
  }
  __syncthreads();
  int wv = tid >> 6, lane = tid & 63, l31 = lane & 31, lh = lane >> 5;
  int st = wv >> 1;       // node subtile (32 nodes)
  int mat = wv & 1;       // 0: Ptop, 1: Pmid
  bf16x8 afr[4];
  #pragma unroll
  for (int ks = 0; ks < 4; ks++) {
    int row = st * 32 + l31;
    afr[ks] = *(const bf16x8*)&vls[row * 64 + ((ks * 16 + lh * 8) ^ ((row & 7) << 3))];
  }
  u16* Pt = mat ? Pmid : Ptop;
  #pragma unroll
  for (int cg = 0; cg < 4; cg++) {
    f32x16 acc;
    #pragma unroll
    for (int i = 0; i < 16; i++) acc[i] = 0.f;
    #pragma unroll
    for (int ks = 0; ks < 4; ks++) {
      bf16x8 b = *(const bf16x8*)&WbF[(((mat * 4 + cg) * 4 + ks) * 64 + lane) * 8];
      acc = __builtin_amdgcn_mfma_f32_32x32x16_bf16(afr[ks], b, acc, 0, 0, 0);
    }
    #pragma unroll
    for (int rg = 0; rg < 16; rg++) {
      int row = (rg & 3) + 8 * (rg >> 2) + 4 * lh;  // C/D layout (m74/m101)
      int node = nb + st * 32 + row;
      if (node < N_NODES)
        Pt[(size_t)node * 128 + cg * 32 + l31] = f2bf(acc[rg]);
    }
  }
}

// ---------------- MFMA edge kernel (half-batched register epilogue) ----------
// 1250 blocks x 5 tiles x 128 edges, 3 blocks/CU. Epilogue batches indices ->
// gathers -> compute in two groups of 8 rg (live gather regs ~48, fits the
// (256,3) ~170-reg budget without spill). B columns permuted so lane l's acc
// quad = (mlp_2c, scr_2c, mlp_{2c+1}, scr_{2c+1}) with c=l&31; C/D row =
// (rg&3)+8*(rg>>2)+4*(l>>5).
__global__ __launch_bounds__(256, 3) void edge_mm_kernel(
    const int* __restrict__ src_s, const int* __restrict__ dst_s,
    const u16* __restrict__ ef_s,
    const u16* __restrict__ Ptop, const u16* __restrict__ Pmid,
    const float* __restrict__ Wm_l, const float* __restrict__ Ws_l,
    u32* __restrict__ y, float* __restrict__ ys1, float* __restrict__ ys2) {
  __shared__ u16 WbF[6144];      // B frags, 12 KB
  __shared__ float red[2048];    // stats reduce, 8 KB
  int tid = threadIdx.x;
  int w = tid >> 6, lane = tid & 63;
  int l31 = lane & 31, lh = lane >> 5;

  // bijective XCD swizzle: each XCD gets a contiguous (dst-sorted) chunk
  int nwg = gridDim.x;
  int q8 = nwg >> 3, r8 = nwg & 7;
  int xcd = blockIdx.x & 7, bidx = blockIdx.x >> 3;
  int bswz = (xcd < r8 ? xcd * (q8 + 1) : r8 * (q8 + 1) + (xcd - r8) * q8) + bidx;

  // stage Wbot as B fragments with column permutation:
  // p = tt*32 + l -> feature col 2l+(tt>>1), half = tt&1 (0:mlp W, 1:scr W)
  for (int t = tid; t < 6144; t += 256) {
    int slot = t >> 3, j = t & 7;
    int tt = slot / 192, rem = slot - tt * 192;
    int ks = rem >> 6, ln = rem & 63;
    int c = 2 * (ln & 31) + (tt >> 1);
    int k = ks * 16 + ((ln >> 5) << 3) + j;
    float val = 0.f;
    if (k < FE) val = (tt & 1) ? Ws_l[(128 + k) * 64 + c] : Wm_l[(128 + k) * 64 + c];
    WbF[t] = f2bf(val);
  }
  __syncthreads();

  float sum4[4] = {0, 0, 0, 0}, ssq4[4] = {0, 0, 0, 0};

  for (int tile = 0; tile < 5; tile++) {
    int T = (bswz * 5 + tile) * 128;
    const u16* ap = ef_s + (size_t)(T + 32 * w + l31) * 48 + lh * 8;
    bf16x8 a0 = *(const bf16x8*)(ap);
    bf16x8 a1 = *(const bf16x8*)(ap + 16);
    bf16x8 a2 = *(const bf16x8*)(ap + 32);
    f32x16 acc0, acc1, acc2, acc3;
    #pragma unroll
    for (int i = 0; i < 16; i++) { acc0[i] = 0.f; acc1[i] = 0.f; acc2[i] = 0.f; acc3[i] = 0.f; }
    #pragma unroll
    for (int ks = 0; ks < 3; ks++) {
      bf16x8 a = (ks == 0) ? a0 : (ks == 1) ? a1 : a2;
      bf16x8 b0 = *(const bf16x8*)&WbF[((0 * 3 + ks) * 64 + lane) * 8];
      bf16x8 b1 = *(const bf16x8*)&WbF[((1 * 3 + ks) * 64 + lane) * 8];
      bf16x8 b2 = *(const bf16x8*)&WbF[((2 * 3 + ks) * 64 + lane) * 8];
      bf16x8 b3 = *(const bf16x8*)&WbF[((3 * 3 + ks) * 64 + lane) * 8];
      acc0 = __builtin_amdgcn_mfma_f32_32x32x16_bf16(a, b0, acc0, 0, 0, 0);
      acc1 = __builtin_amdgcn_mfma_f32_32x32x16_bf16(a, b1, acc1, 0, 0, 0);
      acc2 = __builtin_amdgcn_mfma_f32_32x32x16_bf16(a, b2, acc2, 0, 0, 0);
      acc3 = __builtin_amdgcn_mfma_f32_32x32x16_bf16(a, b3, acc3, 0, 0, 0);
    }
    // half-batched epilogue: two groups of 8 rg (indices -> gathers -> compute)
    #pragma unroll
    for (int hb = 0; hb < 2; hb++) {
      int sv[8], dv[8];
      #pragma unroll
      for (int r8i = 0; r8i < 8; r8i++) {
        int rg = hb * 8 + r8i;
        int row = (rg & 3) + 8 * (rg >> 2) + 4 * lh;  // C/D layout (m74/m101)
        int i = T + 32 * w + row;
        sv[r8i] = src_s[i];
        dv[r8i] = dst_s[i];
      }
      uint2 ptv[8], pmv[8];
      #pragma unroll
      for (int r8i = 0; r8i < 8; r8i++)
        ptv[r8i] = *(const uint2*)((const u32*)Ptop + (size_t)sv[r8i] * 64 + 2 * l31);
      #pragma unroll
      for (int r8i = 0; r8i < 8; r8i++)
        pmv[r8i] = *(const uint2*)((const u32*)Pmid + (size_t)dv[r8i] * 64 + 2 * l31);
      #pragma unroll
      for (int r8i = 0; r8i < 8; r8i++) {
        int rg = hb * 8 + r8i;
        int row = (rg & 3) + 8 * (rg >> 2) + 4 * lh;
        int i = T + 32 * w + row;
        float g0, g1, g2, g3;
        if (hb == 0) { g0 = acc0[r8i]; g1 = acc1[r8i]; g2 = acc2[r8i]; g3 = acc3[r8i]; }
        else         { g0 = acc0[8 + r8i]; g1 = acc1[8 + r8i]; g2 = acc2[8 + r8i]; g3 = acc3[8 + r8i]; }
        float ym0 = g0 + bf2f((u16)ptv[r8i].x) + bf2f((u16)pmv[r8i].x);
        float ysv0 = g1 + bf2f((u16)(ptv[r8i].x >> 16)) + bf2f((u16)(pmv[r8i].x >> 16));
        float ym1 = g2 + bf2f((u16)ptv[r8i].y) + bf2f((u16)pmv[r8i].y);
        float ysv1 = g3 + bf2f((u16)(ptv[r8i].y >> 16)) + bf2f((u16)(pmv[r8i].y >> 16));
        ((ushort4*)y)[(size_t)i * 32 + l31] =
            make_ushort4(f2bf(ym0), f2bf(ysv0), f2bf(ym1), f2bf(ysv1));
        sum4[0] += ym0; sum4[1] += ysv0; sum4[2] += ym1; sum4[3] += ysv1;
        ssq4[0] += ym0 * ym0; ssq4[1] += ysv0 * ysv0;
        ssq4[2] += ym1 * ym1; ssq4[3] += ysv1 * ysv1;
      }
    }
  }
  // block-reduce stats in interleaved col space ic = 4*l31 + j
  // (j: 0=mlp 2c, 1=scr 2c, 2=mlp 2c+1, 3=scr 2c+1, c=l31)
  __syncthreads();
  int slotw = w * 2 + lh;  // 8 groups of 32 lanes, each holds 4 cols
  #pragma unroll
  for (int j = 0; j < 4; j++) {
    red[slotw * 128 + l31 * 4 + j] = sum4[j];
    red[1024 + slotw * 128 + l31 * 4 + j] = ssq4[j];
  }
  __syncthreads();
  int part = blockIdx.x & (NPART - 1);
  if (tid < 128) {
    float s = 0;
    #pragma unroll
    for (int g = 0; g < 8; g++) s += red[g * 128 + tid];
    atomicAdd(&ys1[part * 128 + tid], s);
  } else {
    int cc = tid - 128;
    float s = 0;
    #pragma unroll
    for (int g = 0; g < 8; g++) s += red[1024 + g * 128 + cc];
    atomicAdd(&ys2[part * 128 + cc], s);
  }
}

// ---------------- aggregate (CSR, 4 nodes/wave, 8-slot partial stats) --------
// y entry (i, c) = u32 (bf16 mlp_c | bf16 scr_c<<16)
// ys1/ys2: [NPART][128] partials; as1/as2: [NPART][64] partials.

__global__ void aggregate_kernel(const u32* __restrict__ y, const int* __restrict__ row_ptr,
                                 const float* ys1, const float* ys2,
                                 const float* gm_l, const float* bem_l,
                                 const float* gs_l, const float* bes_l,
                                 float* __restrict__ agg, float* as1, float* as2) {
  __shared__ float aS[128], cS[128];
  __shared__ float ps[4][64], pq2[4][64];
  int tid = threadIdx.x;
  if (tid < 128) {
    float sA = 0, sB = 0;
    #pragma unroll
    for (int p = 0; p < NPART; p++) { sA += ys1[p * 128 + tid]; sB += ys2[p * 128 + tid]; }
    int cc = tid >> 1, scr = tid & 1;
    float mean = sA * (1.0f / M_EDGES);
    float var = sB * (1.0f / M_EDGES) - mean * mean;
    float g = scr ? gs_l[cc] : gm_l[cc];
    float b = scr ? bes_l[cc] : bem_l[cc];
    float av = g * rsqrtf(var + EPS);
    aS[tid] = av; cS[tid] = b - mean * av;
  }
  __syncthreads();
  int wv = tid >> 6, lane = tid & 63;
  float am = aS[2 * lane], cm = cS[2 * lane];
  float as_ = aS[2 * lane + 1], cs = cS[2 * lane + 1];
  const u32* yc = y + lane;
  float sSum = 0, sSq = 0;
  #pragma unroll
  for (int k = 0; k < 4; k++) {
    int n = blockIdx.x * 16 + wv * 4 + k;
    int i0 = row_ptr[n], i1 = row_ptr[n + 1];
    float accA = 0, accB = 0;
    int i = i0;
    for (; i + 2 <= i1; i += 2) {
      u32 wa = yc[(size_t)i * 64];
      u32 wb = yc[(size_t)(i + 1) * 64];
      accA += sigmoidf_(fmaf(am, bf2f((u16)wa), cm)) *
              softplusf_(fmaf(as_, bf2f((u16)(wa >> 16)), cs));
      accB += sigmoidf_(fmaf(am, bf2f((u16)wb), cm)) *
              softplusf_(fmaf(as_, bf2f((u16)(wb >> 16)), cs));
    }
    if (i < i1) {
      u32 wa = yc[(size_t)i * 64];
      accA += sigmoidf_(fmaf(am, bf2f((u16)wa), cm)) *
              softplusf_(fmaf(as_, bf2f((u16)(wa >> 16)), cs));
    }
    float acc = accA + accB;
    agg[(size_t)n * 64 + lane] = acc;
    sSum += acc; sSq += acc * acc;
  }
  ps[wv][lane] = sSum; pq2[wv][lane] = sSq;
  __syncthreads();
  if (tid < 64) {
    float s = ps[0][tid] + ps[1][tid] + ps[2][tid] + ps[3][tid];
    float q = pq2[0][tid] + pq2[1][tid] + pq2[2][tid] + pq2[3][tid];
    int part = blockIdx.x & (NPART - 1);
    atomicAdd(&as1[part * 64 + tid], s);
    atomicAdd(&as2[part * 64 + tid], q);
  }
}

// plain node update (last layer); s1/s2 are [NPART][64] partials
__global__ void node_update_kernel(const float* agg, const float* s1, const float* s2,
                                   const float* gn_l, const float* ben_l, float* v) {
  __shared__ float aS[64], cS[64];
  int tid = threadIdx.x;
  if (tid < 64) {
    float sA = 0, sB = 0;
    #pragma unroll
    for (int p = 0; p < NPART; p++) { sA += s1[p * 64 + tid]; sB += s2[p * 64 + tid]; }
    float mean = sA * (1.0f / N_NODES);
    float var = sB * (1.0f / N_NODES) - mean * mean;
    float av = gn_l[tid] * rsqrtf(var + EPS);
    aS[tid] = av; cS[tid] = ben_l[tid] - mean * av;
  }
  __syncthreads();
  int idx = blockIdx.x * 256 + tid;  // N*64 exact
  int c = idx & 63;
  v[idx] = softplusf_(aS[c] * agg[idx] + cS[c] + v[idx]);
}

// ---------------- pooling + readout ----------------

__global__ void pool_sum_kernel(const float* v, const int* gid, float* psum, float* pcnt) {
  int tid = threadIdx.x;
  int g = blockIdx.x * 4 + (tid >> 6);
  int lane = tid & 63;
  int n0 = g * 64;
  if (n0 >= N_NODES) return;
  int n1 = min(n0 + 64, N_NODES);
  int cur = gid[n0];
  float acc = 0;
  int runlen = 0;
  for (int n = n0; n < n1; n++) {
    int gg = gid[n];
    if (gg != cur) {
      atomicAdd(&psum[cur * 64 + lane], acc);
      if (lane == 0) atomicAdd(&pcnt[cur], (float)runlen);
      acc = 0; runlen = 0; cur = gg;
    }
    acc += v[n * 64 + lane];
    runlen++;
  }
  atomicAdd(&psum[cur * 64 + lane], acc);
  if (lane == 0) atomicAdd(&pcnt[cur], (float)runlen);
}

__global__ void ro_mm1_kernel(const float* psum, const float* pcnt, const float* Wf0, float* y1) {
  int t = blockIdx.x * 256 + threadIdx.x;  // 256*32
  int row = t >> 5, q = t & 31;
  float inv = 1.0f / fmaxf(pcnt[row], 1.0f);
  float a0 = 0, a1 = 0, a2 = 0, a3 = 0;
  #pragma unroll 4
  for (int k = 0; k < 64; k++) {
    float x = psum[row * 64 + k] * inv;
    float4 w = *(const float4*)&Wf0[k * 128 + q * 4];
    a0 = fmaf(x, w.x, a0); a1 = fmaf(x, w.y, a1);
    a2 = fmaf(x, w.z, a2); a3 = fmaf(x, w.w, a3);
  }
  float4 r; r.x = a0; r.y = a1; r.z = a2; r.w = a3;
  *(float4*)&y1[row * 128 + q * 4] = r;
}

__global__ void ro_mm2_kernel(const float* y1, const float* gf0, const float* bef0,
                              const float* Wf1, float* y2) {
  __shared__ float aS[128], cS[128], pS[2][128], pQ[2][128];
  int tid = threadIdx.x;
  int c = tid & 127, h = tid >> 7;
  float s = 0, ss = 0;
  for (int rr = h * 128; rr < h * 128 + 128; rr++) {
    float x = y1[rr * 128 + c];
    s += x; ss += x * x;
  }
  pS[h][c] = s; pQ[h][c] = ss;
  __syncthreads();
  if (tid < 128) {
    float S = pS[0][tid] + pS[1][tid], Q = pQ[0][tid] + pQ[1][tid];
    float mean = S * (1.0f / 256.0f), var = Q * (1.0f / 256.0f) - mean * mean;
    float av = gf0[tid] * rsqrtf(var + EPS);
    aS[tid] = av; cS[tid] = bef0[tid] - mean * av;
  }
  __syncthreads();
  int t = blockIdx.x * 256 + tid;  // 256*16
  int row = t >> 4, q = t & 15;
  float a0 = 0, a1 = 0, a2 = 0, a3 = 0;
  #pragma unroll 4
  for (int k = 0; k < 128; k++) {
    float act = siluf_(fmaf(aS[k], y1[row * 128 + k], cS[k]));
    float4 w = *(const float4*)&Wf1[k * 64 + q * 4];
    a0 = fmaf(act, w.x, a0); a1 = fmaf(act, w.y, a1);
    a2 = fmaf(act, w.z, a2); a3 = fmaf(act, w.w, a3);
  }
  float4 r; r.x = a0; r.y = a1; r.z = a2; r.w = a3;
  *(float4*)&y2[row * 64 + q * 4] = r;
}

__global__ void ro_out_kernel(const float* y2, const float* gf1, const float* bef1,
                              const float* Wt, const float* bt, float* out) {
  __shared__ float aS[64], cS[64], pS[4][64], pQ[4][64];
  int tid = threadIdx.x;
  int c = tid & 63, h = tid >> 6;
  float s = 0, ss = 0;
  for (int rr = h * 64; rr < h * 64 + 64; rr++) {
    float x = y2[rr * 64 + c];
    s += x; ss += x * x;
  }
  pS[h][c] = s; pQ[h][c] = ss;
  __syncthreads();
  if (tid < 64) {
    float S = pS[0][tid] + pS[1][tid] + pS[2][tid] + pS[3][tid];
    float Q = pQ[0][tid] + pQ[1][tid] + pQ[2][tid] + pQ[3][tid];
    float mean = S * (1.0f / 256.0f), var = Q * (1.0f / 256.0f) - mean * mean;
    float av = gf1[tid] * rsqrtf(var + EPS);
    aS[tid] = av; cS[tid] = bef1[tid] - mean * av;
  }
  __syncthreads();
  float acc = bt[0];
  #pragma unroll 4
  for (int cc = 0; cc < 64; cc++)
    acc += siluf_(fmaf(aS[cc], y2[tid * 64 + cc], cS[cc])) * Wt[cc];
  out[tid] = acc;
}

// ---------------- host ----------------

extern "C" void kernel_launch(void* const* d_in, const int* in_sizes, int n_in,
                              void* d_out, int out_size, void* d_ws, size_t ws_size,
                              hipStream_t stream) {
  const float* node_feats = (const float*)d_in[0];
  const float* edge_feats = (const float*)d_in[1];
  const int* src = (const int*)d_in[2];
  const int* dst = (const int*)d_in[3];
  const int* gid = (const int*)d_in[4];
  const float* W_emb = (const float*)d_in[5];
  const float* g_emb = (const float*)d_in[7];
  const float* be_emb = (const float*)d_in[8];
  const float* Wm = (const float*)d_in[9];
  const float* gm = (const float*)d_in[11];
  const float* bem = (const float*)d_in[12];
  const float* Wsc = (const float*)d_in[13];
  const float* gs = (const float*)d_in[15];
  const float* bes = (const float*)d_in[16];
  const float* gn = (const float*)d_in[17];
  const float* ben = (const float*)d_in[18];
  const float* Wf0 = (const float*)d_in[19];
  const float* gf0 = (const float*)d_in[21];
  const float* bef0 = (const float*)d_in[22];
  const float* Wf1 = (const float*)d_in[23];
  const float* gf1 = (const float*)d_in[25];
  const float* bef1 = (const float*)d_in[26];
  const float* Wt = (const float*)d_in[27];
  const float* bt = (const float*)d_in[28];
  float* out = (float*)d_out;

  char* ws = (char*)d_ws;
  size_t off = 0;
  auto alloc = [&](size_t bytes) -> void* {
    void* p = ws + off;
    off = (off + bytes + 511) & ~(size_t)511;
    return p;
  };
  u16* ef_s   = (u16*)alloc((size_t)M_EDGES * 48 * 2);   // padded, bf16
  u32* ybuf   = (u32*)alloc((size_t)M_EDGES * 64 * 4);   // interleaved (mlp|scr) pairs
  u16* Ptop   = (u16*)alloc((size_t)N_NODES * 128 * 2);  // interleaved bf16 tables
  u16* Pmid   = (u16*)alloc((size_t)N_NODES * 128 * 2);
  float* vbuf = (float*)alloc((size_t)N_NODES * 64 * 4);
  float* nbuf = (float*)alloc((size_t)N_NODES * 64 * 4);
  int* row_ptr = (int*)alloc((size_t)(N_NODES + 1) * 4);
  int* nexts   = (int*)alloc((size_t)N_NODES * 4);
  int* eid_s   = (int*)alloc((size_t)M_EDGES * 4);
  int* src_s   = (int*)alloc((size_t)M_EDGES * 4);
  int* dst_s   = (int*)alloc((size_t)M_EDGES * 4);
  int* bsum    = (int*)alloc(256 * 4);
  int* boffs   = (int*)alloc(256 * 4);
  float* stats = (float*)alloc((size_t)80000 * 4);
  (void)ws_size; (void)in_sizes; (void)n_in; (void)out_size;

  // stats region layout (floats); [0, 26880) zeroed each call
  float* emb_p1 = stats + 0;       // [8][64]
  float* emb_p2 = stats + 512;     // [8][64]
  float* ys_p1  = stats + 1024;    // NL x [8][128]
  float* ys_p2  = stats + 4096;    // NL x [8][128]
  float* as_p1  = stats + 7168;    // NL x [8][64]
  float* as_p2  = stats + 8704;    // NL x [8][64]
  float* pcnt   = stats + 10240;   // 256
  float* psum   = stats + 10496;   // 256*64 -> ends 26880
  float* rb1    = stats + 26880;   // 256*128
  float* rb2    = stats + 59648;   // 256*64 -> ends 76032

  // preprocessing
  zero_kernel<<<196, 256, 0, stream>>>(nexts, stats, N_NODES, 26880);
  hist_kernel<<<3125, 256, 0, stream>>>(dst, nexts);
  scanA_kernel<<<196, 256, 0, stream>>>(nexts, bsum);
  scanB_kernel<<<1, 256, 0, stream>>>(bsum, boffs, row_ptr);
  scanC_kernel<<<196, 256, 0, stream>>>(nexts, boffs, row_ptr, nexts);
  scatter_kernel<<<3125, 256, 0, stream>>>(src, dst, nexts, eid_s);
  permute_ef_kernel<<<25000, 256, 0, stream>>>(edge_feats, eid_s, src, dst,
                                               ef_s, src_s, dst_s);

  // embedding (stats fused, 8-slot partials)
  emb_mm_kernel<<<3125, 256, 0, stream>>>(node_feats, W_emb, nbuf, emb_p1, emb_p2);
  finv_ptab_kernel<<<782, 256, 0, stream>>>(nbuf, vbuf, emb_p1, emb_p2, g_emb, be_emb,
                                            Wm, Wsc, Ptop, Pmid, 1.0f / N_NODES, 0);

  for (int l = 0; l < NL; l++) {
    const float* Wm_l = Wm + (size_t)l * 169 * 64;
    const float* Ws_l = Wsc + (size_t)l * 169 * 64;
    edge_mm_kernel<<<1250, 256, 0, stream>>>(src_s, dst_s, ef_s, Ptop, Pmid,
                                             Wm_l, Ws_l, ybuf,
                                             ys_p1 + l * 1024, ys_p2 + l * 1024);
    aggregate_kernel<<<3125, 256, 0, stream>>>(ybuf, row_ptr,
                                               ys_p1 + l * 1024, ys_p2 + l * 1024,
                                               gm + l * 64, bem + l * 64,
                                               gs + l * 64, bes + l * 64, nbuf,
                                               as_p1 + l * 512, as_p2 + l * 512);
    if (l < NL - 1) {
      finv_ptab_kernel<<<782, 256, 0, stream>>>(nbuf, vbuf,
                                                as_p1 + l * 512, as_p2 + l * 512,
                                                gn + l * 64, ben + l * 64,
                                                Wm + (size_t)(l + 1) * 169 * 64,
                                                Wsc + (size_t)(l + 1) * 169 * 64,
                                                Ptop, Pmid, 1.0f / N_NODES, 1);
    } else {
      node_update_kernel<<<12500, 256, 0, stream>>>(nbuf,
                                                    as_p1 + l * 512, as_p2 + l * 512,
                                                    gn + l * 64, ben + l * 64, vbuf);
    }
  }

  // pooling + readout
  pool_sum_kernel<<<196, 256, 0, stream>>>(vbuf, gid, psum, pcnt);
  ro_mm1_kernel<<<32, 256, 0, stream>>>(psum, pcnt, Wf0, rb1);
  ro_mm2_kernel<<<16, 256, 0, stream>>>(rb1, gf0, bef0, Wf1, rb2);
  ro_out_kernel<<<1, 256, 0, stream>>>(rb2, gf1, bef1, Wt, bt, out);
}

// Round 13
// 1144.955 us; speedup vs baseline: 1.0460x; 1.0460x over previous
//
#include <hip/hip_runtime.h>
#include <stdint.h>

// CGCNN forward, round 13:
//  - edge_mm: reverted to round-11 optimum (256,2), full-batched epilogue,
//    1250x5 tiles (round-12 falsified the spill theory: 3 blk/CU re-inflates
//    gather traffic FETCH 135->207; 2 blk/CU is the measured optimum).
//  - aggregate: parity/uint2 rewrite. Wave splits into two edge-parity groups
//    (i=i0+p; i+=2); each lane loads uint2 (cols 2c,2c+1 of its parity edge):
//    load instrs halved, 512B contiguous per wave-step, 4 independent
//    acc chains; parity halves merged via __shfl_xor(32) per node.
// Biases before BN cancel exactly -> skipped.

#define N_NODES 50000
#define M_EDGES 800000
#define FV 92
#define FE 41
#define EMB 64
#define NL 3
#define EPS 1e-5f
#define NPART 8

typedef unsigned short u16;
typedef unsigned int u32;
typedef __attribute__((ext_vector_type(8))) short bf16x8;
typedef __attribute__((ext_vector_type(16))) float f32x16;

__device__ __forceinline__ float bf2f(u16 u) {
  return __uint_as_float(((u32)u) << 16);
}
__device__ __forceinline__ u16 f2bf(float f) {
  u32 x = __float_as_uint(f);
  return (u16)((x + 0x7fffu + ((x >> 16) & 1u)) >> 16);
}
__device__ __forceinline__ float sigmoidf_(float x) { return 1.0f / (1.0f + __expf(-x)); }
__device__ __forceinline__ float softplusf_(float x) {
  return fmaxf(x, 0.f) + __logf(1.f + __expf(-fabsf(x)));
}
__device__ __forceinline__ float siluf_(float x) { return x * sigmoidf_(x); }

// ---------------- preprocessing ----------------

__global__ void zero_kernel(int* nexts, float* stats, int nInts, int nFloats) {
  int i = blockIdx.x * 256 + threadIdx.x;
  if (i < nInts) nexts[i] = 0;
  if (i < nFloats) stats[i] = 0.f;
}

__global__ void hist_kernel(const int* dst, int* hist) {
  int e = blockIdx.x * 256 + threadIdx.x;
  if (e < M_EDGES) atomicAdd(&hist[dst[e]], 1);
}

__global__ void scanA_kernel(const int* hist, int* bsum) {
  int tid = threadIdx.x;
  int i = blockIdx.x * 256 + tid;
  int x = (i < N_NODES) ? hist[i] : 0;
  #pragma unroll
  for (int o = 32; o > 0; o >>= 1) x += __shfl_xor(x, o);
  __shared__ int wsm[4];
  if ((tid & 63) == 0) wsm[tid >> 6] = x;
  __syncthreads();
  if (tid == 0) bsum[blockIdx.x] = wsm[0] + wsm[1] + wsm[2] + wsm[3];
}

__global__ void scanB_kernel(const int* bsum, int* boffs, int* row_ptr) {
  int tid = threadIdx.x;
  int lane = tid & 63, wid = tid >> 6;
  int x = (tid < 196) ? bsum[tid] : 0;
  int v = x;
  #pragma unroll
  for (int o = 1; o < 64; o <<= 1) {
    int nv = __shfl_up(v, o);
    if (lane >= o) v += nv;
  }
  __shared__ int wsm[4];
  if (lane == 63) wsm[wid] = v;
  __syncthreads();
  int add = 0;
  for (int wq = 0; wq < wid; wq++) add += wsm[wq];
  if (tid < 196) boffs[tid] = v + add - x;  // exclusive
  if (tid == 0) row_ptr[N_NODES] = M_EDGES;
}

__global__ void scanC_kernel(const int* hist, const int* boffs, int* row_ptr, int* nexts) {
  int tid = threadIdx.x;
  int i = blockIdx.x * 256 + tid;
  int lane = tid & 63, wid = tid >> 6;
  int x = (i < N_NODES) ? hist[i] : 0;
  int v = x;
  #pragma unroll
  for (int o = 1; o < 64; o <<= 1) {
    int nv = __shfl_up(v, o);
    if (lane >= o) v += nv;
  }
  __shared__ int wsm[4];
  if (lane == 63) wsm[wid] = v;
  __syncthreads();
  int add = boffs[blockIdx.x];
  for (int wq = 0; wq < wid; wq++) add += wsm[wq];
  int excl = v - x + add;
  if (i < N_NODES) { row_ptr[i] = excl; nexts[i] = excl; }
}

__global__ void scatter_kernel(const int* src, const int* dst, int* nexts, int* eid_s) {
  int e = blockIdx.x * 256 + threadIdx.x;
  if (e < M_EDGES) {
    int p = atomicAdd(&nexts[dst[e]], 1);
    eid_s[p] = e;
  }
}

// gather-direction permute (coalesced writes, zero-padded 48 cols) +
// materialize src_s/dst_s (random L2 reads, coalesced writes)
__global__ void permute_ef_kernel(const float* ef, const int* eid_s,
                                  const int* src, const int* dst,
                                  u16* ef_s, int* src_s, int* dst_s) {
  int tid = threadIdx.x;
  u32 p = blockIdx.x * 32 + (tid >> 3);  // 25000 blocks * 32 rows = M
  int q = tid & 7;
  int e = eid_s[p];
  if (q == 0) { src_s[p] = src[e]; dst_s[p] = dst[e]; }
  const float* base = ef + (size_t)e * 41;
  u32* orow = (u32*)ef_s + (size_t)p * 24 + q * 3;
  #pragma unroll
  for (int i = 0; i < 3; i++) {
    int k = q * 6 + i * 2;
    float lo = (k < 41) ? base[k] : 0.f;
    float hi = (k + 1 < 41) ? base[k + 1] : 0.f;
    orow[i] = (u32)f2bf(lo) | ((u32)f2bf(hi) << 16);
  }
}

// ---------------- embedding (matmul + fused column stats, 8-slot partials) ---

__global__ void emb_mm_kernel(const float* nf, const float* Wemb, float* y0,
                              float* s1, float* s2) {
  __shared__ float Wl[FV][EMB];          // 23.5 KB
  __shared__ float ps[16][64], pq2[16][64];  // 8 KB
  int tid = threadIdx.x;
  for (int idx = tid; idx < FV * EMB; idx += 256) Wl[idx >> 6][idx & 63] = Wemb[idx];
  __syncthreads();
  int t = blockIdx.x * 256 + tid;  // N*16
  int n = t >> 4, q = t & 15;
  const float* row = nf + n * FV;
  float a0 = 0, a1 = 0, a2 = 0, a3 = 0;
  #pragma unroll 4
  for (int k = 0; k < FV; k++) {
    float x = row[k];
    float4 w = *(const float4*)&Wl[k][q * 4];
    a0 = fmaf(x, w.x, a0); a1 = fmaf(x, w.y, a1);
    a2 = fmaf(x, w.z, a2); a3 = fmaf(x, w.w, a3);
  }
  float4 r; r.x = a0; r.y = a1; r.z = a2; r.w = a3;
  *(float4*)&y0[n * EMB + q * 4] = r;
  int nl = tid >> 4, q4 = (tid & 15) * 4;
  ps[nl][q4] = a0; ps[nl][q4 + 1] = a1; ps[nl][q4 + 2] = a2; ps[nl][q4 + 3] = a3;
  pq2[nl][q4] = a0 * a0; pq2[nl][q4 + 1] = a1 * a1;
  pq2[nl][q4 + 2] = a2 * a2; pq2[nl][q4 + 3] = a3 * a3;
  __syncthreads();
  if (tid < 64) {
    float s = 0, ss = 0;
    #pragma unroll
    for (int g = 0; g < 16; g++) { s += ps[g][tid]; ss += pq2[g][tid]; }
    int part = blockIdx.x & (NPART - 1);
    atomicAdd(&s1[part * 64 + tid], s);
    atomicAdd(&s2[part * 64 + tid], ss);
  }
}

// ---------------- fused BN-finalize + v activation + P tables (MFMA) --------
// mode 0: v = silu(bn(X)); mode 1: v = softplus(bn(X)+v). Then P = v @ W
// halves via mfma_32x32x16_bf16. 64 nodes/block, grid 782 (tail guarded).
// vls: bf16 v rows XOR-swizzled (u16 idx = c ^ ((row&7)<<3)) -> conflict-free
// ds_read_b128 A-frags. WbF: B-frags (lane l: col=l&31, k=ks*16+(l>>5)*8+j),
// interleaved cols ic=cg*32+l31 -> feature ic>>1, table-half ic&1.
// P write: u16 at [node*128 + cg*32 + l31] (64 B contiguous per half-wave).

__global__ __launch_bounds__(256) void finv_ptab_kernel(
    const float* __restrict__ X, float* __restrict__ vio,
    const float* s1, const float* s2, const float* g, const float* be,
    const float* __restrict__ Wm_l, const float* __restrict__ Ws_l,
    u16* __restrict__ Ptop, u16* __restrict__ Pmid, float minv, int mode) {
  __shared__ u16 vls[64 * 64];   // 8 KB
  __shared__ u16 WbF[16384];     // 32 KB: [mat][cg][ks][lane]*8
  __shared__ float aS[64], cS[64];
  int tid = threadIdx.x;
  if (tid < 64) {
    float sA = 0, sB = 0;
    #pragma unroll
    for (int p = 0; p < NPART; p++) { sA += s1[p * 64 + tid]; sB += s2[p * 64 + tid]; }
    float mean = sA * minv;
    float var = sB * minv - mean * mean;
    float av = g[tid] * rsqrtf(var + EPS);
    aS[tid] = av; cS[tid] = be[tid] - mean * av;
  }
  __syncthreads();
  int nb = blockIdx.x * 64;
  #pragma unroll
  for (int it = 0; it < 16; it++) {
    int idx = it * 256 + tid;
    int nl = idx >> 6, c = idx & 63;
    int n = nb + nl;
    float vn = 0.f;
    if (n < N_NODES) {
      size_t gi = (size_t)n * 64 + c;
      float z = fmaf(aS[c], X[gi], cS[c]);
      vn = mode ? softplusf_(z + vio[gi]) : siluf_(z);
      vio[gi] = vn;
    }
    vls[nl * 64 + (c ^ ((nl & 7) << 3))] = f2bf(vn);
  }
  // stage W as B-frags for both table halves (mat 0: W rows 0..63 -> Ptop;
  // mat 1: rows 64..127 -> Pmid)
  for (int t = tid; t < 16384; t += 256) {
    int slot = t >> 3, j = t & 7;
    int mat = slot >> 10;
    int rem = slot & 1023;
    int cg = rem >> 8;
    int rem2 = rem & 255;
    int ks = rem2 >> 6, ln = rem2 & 63;
    int ic = cg * 32 + (ln & 31);
    int feat = ic >> 1, scr = ic & 1;
    int k = ks * 16 + ((ln >> 5) << 3) + j;
    int wrow = mat * 64 + k;
    float val = scr ? Ws_l[wrow * 64 + feat] : Wm_l[wrow * 64 + feat];
    WbF[t] = f2bf(val);
  }
  __syncthreads();
  int wv = tid >> 6, lane = tid & 63, l31 = lane & 31, lh = lane >> 5;
  int st = wv >> 1;       // node subtile (32 nodes)
  int mat = wv & 1;       // 0: Ptop, 1: Pmid
  bf16x8 afr[4];
  #pragma unroll
  for (int ks = 0; ks < 4; ks++) {
    int row = st * 32 + l31;
    afr[ks] = *(const bf16x8*)&vls[row * 64 + ((ks * 16 + lh * 8) ^ ((row & 7) << 3))];
  }
  u16* Pt = mat ? Pmid : Ptop;
  #pragma unroll
  for (int cg = 0; cg < 4; cg++) {
    f32x16 acc;
    #pragma unroll
    for (int i = 0; i < 16; i++) acc[i] = 0.f;
    #pragma unroll
    for (int ks = 0; ks < 4; ks++) {
      bf16x8 b = *(const bf16x8*)&WbF[(((mat * 4 + cg) * 4 + ks) * 64 + lane) * 8];
      acc = __builtin_amdgcn_mfma_f32_32x32x16_bf16(afr[ks], b, acc, 0, 0, 0);
    }
    #pragma unroll
    for (int rg = 0; rg < 16; rg++) {
      int row = (rg & 3) + 8 * (rg >> 2) + 4 * lh;  // C/D layout (m74/m101)
      int node = nb + st * 32 + row;
      if (node < N_NODES)
        Pt[(size_t)node * 128 + cg * 32 + l31] = f2bf(acc[rg]);
    }
  }
}

// ---------------- MFMA edge kernel (batched register epilogue) ---------------
// 1250 blocks x 5 tiles x 128 edges, 2 blocks/CU (measured optimum: higher
// concurrency re-inflates gather traffic, rounds 9/12). Epilogue batches ALL
// index loads, then ALL 32 row-gathers into registers (memory ILP), then
// computes/stores. B columns permuted so lane l's acc quad = (mlp_2c, scr_2c,
// mlp_{2c+1}, scr_{2c+1}) with c=l&31; C/D row = (rg&3)+8*(rg>>2)+4*(l>>5).
__global__ __launch_bounds__(256, 2) void edge_mm_kernel(
    const int* __restrict__ src_s, const int* __restrict__ dst_s,
    const u16* __restrict__ ef_s,
    const u16* __restrict__ Ptop, const u16* __restrict__ Pmid,
    const float* __restrict__ Wm_l, const float* __restrict__ Ws_l,
    u32* __restrict__ y, float* __restrict__ ys1, float* __restrict__ ys2) {
  __shared__ u16 WbF[6144];      // B frags, 12 KB
  __shared__ float red[2048];    // stats reduce, 8 KB
  int tid = threadIdx.x;
  int w = tid >> 6, lane = tid & 63;
  int l31 = lane & 31, lh = lane >> 5;

  // bijective XCD swizzle: each XCD gets a contiguous (dst-sorted) chunk
  int nwg = gridDim.x;
  int q8 = nwg >> 3, r8 = nwg & 7;
  int xcd = blockIdx.x & 7, bidx = blockIdx.x >> 3;
  int bswz = (xcd < r8 ? xcd * (q8 + 1) : r8 * (q8 + 1) + (xcd - r8) * q8) + bidx;

  // stage Wbot as B fragments with column permutation:
  // p = tt*32 + l -> feature col 2l+(tt>>1), half = tt&1 (0:mlp W, 1:scr W)
  for (int t = tid; t < 6144; t += 256) {
    int slot = t >> 3, j = t & 7;
    int tt = slot / 192, rem = slot - tt * 192;
    int ks = rem >> 6, ln = rem & 63;
    int c = 2 * (ln & 31) + (tt >> 1);
    int k = ks * 16 + ((ln >> 5) << 3) + j;
    float val = 0.f;
    if (k < FE) val = (tt & 1) ? Ws_l[(128 + k) * 64 + c] : Wm_l[(128 + k) * 64 + c];
    WbF[t] = f2bf(val);
  }
  __syncthreads();

  float sum4[4] = {0, 0, 0, 0}, ssq4[4] = {0, 0, 0, 0};

  for (int tile = 0; tile < 5; tile++) {
    int T = (bswz * 5 + tile) * 128;
    const u16* ap = ef_s + (size_t)(T + 32 * w + l31) * 48 + lh * 8;
    bf16x8 a0 = *(const bf16x8*)(ap);
    bf16x8 a1 = *(const bf16x8*)(ap + 16);
    bf16x8 a2 = *(const bf16x8*)(ap + 32);
    f32x16 acc0, acc1, acc2, acc3;
    #pragma unroll
    for (int i = 0; i < 16; i++) { acc0[i] = 0.f; acc1[i] = 0.f; acc2[i] = 0.f; acc3[i] = 0.f; }
    #pragma unroll
    for (int ks = 0; ks < 3; ks++) {
      bf16x8 a = (ks == 0) ? a0 : (ks == 1) ? a1 : a2;
      bf16x8 b0 = *(const bf16x8*)&WbF[((0 * 3 + ks) * 64 + lane) * 8];
      bf16x8 b1 = *(const bf16x8*)&WbF[((1 * 3 + ks) * 64 + lane) * 8];
      bf16x8 b2 = *(const bf16x8*)&WbF[((2 * 3 + ks) * 64 + lane) * 8];
      bf16x8 b3 = *(const bf16x8*)&WbF[((3 * 3 + ks) * 64 + lane) * 8];
      acc0 = __builtin_amdgcn_mfma_f32_32x32x16_bf16(a, b0, acc0, 0, 0, 0);
      acc1 = __builtin_amdgcn_mfma_f32_32x32x16_bf16(a, b1, acc1, 0, 0, 0);
      acc2 = __builtin_amdgcn_mfma_f32_32x32x16_bf16(a, b2, acc2, 0, 0, 0);
      acc3 = __builtin_amdgcn_mfma_f32_32x32x16_bf16(a, b3, acc3, 0, 0, 0);
    }
    // batched epilogue: indices -> gathers -> compute
    int sv[16], dv[16];
    #pragma unroll
    for (int rg = 0; rg < 16; rg++) {
      int row = (rg & 3) + 8 * (rg >> 2) + 4 * lh;  // C/D layout (m74/m101)
      int i = T + 32 * w + row;
      sv[rg] = src_s[i];
      dv[rg] = dst_s[i];
    }
    uint2 ptv[16], pmv[16];
    #pragma unroll
    for (int rg = 0; rg < 16; rg++)
      ptv[rg] = *(const uint2*)((const u32*)Ptop + (size_t)sv[rg] * 64 + 2 * l31);
    #pragma unroll
    for (int rg = 0; rg < 16; rg++)
      pmv[rg] = *(const uint2*)((const u32*)Pmid + (size_t)dv[rg] * 64 + 2 * l31);
    #pragma unroll
    for (int rg = 0; rg < 16; rg++) {
      int row = (rg & 3) + 8 * (rg >> 2) + 4 * lh;
      int i = T + 32 * w + row;
      float ym0 = acc0[rg] + bf2f((u16)ptv[rg].x) + bf2f((u16)pmv[rg].x);
      float ysv0 = acc1[rg] + bf2f((u16)(ptv[rg].x >> 16)) + bf2f((u16)(pmv[rg].x >> 16));
      float ym1 = acc2[rg] + bf2f((u16)ptv[rg].y) + bf2f((u16)pmv[rg].y);
      float ysv1 = acc3[rg] + bf2f((u16)(ptv[rg].y >> 16)) + bf2f((u16)(pmv[rg].y >> 16));
      ((ushort4*)y)[(size_t)i * 32 + l31] =
          make_ushort4(f2bf(ym0), f2bf(ysv0), f2bf(ym1), f2bf(ysv1));
      sum4[0] += ym0; sum4[1] += ysv0; sum4[2] += ym1; sum4[3] += ysv1;
      ssq4[0] += ym0 * ym0; ssq4[1] += ysv0 * ysv0;
      ssq4[2] += ym1 * ym1; ssq4[3] += ysv1 * ysv1;
    }
  }
  // block-reduce stats in interleaved col space ic = 4*l31 + j
  // (j: 0=mlp 2c, 1=scr 2c, 2=mlp 2c+1, 3=scr 2c+1, c=l31)
  __syncthreads();
  int slotw = w * 2 + lh;  // 8 groups of 32 lanes, each holds 4 cols
  #pragma unroll
  for (int j = 0; j < 4; j++) {
    red[slotw * 128 + l31 * 4 + j] = sum4[j];
    red[1024 + slotw * 128 + l31 * 4 + j] = ssq4[j];
  }
  __syncthreads();
  int part = blockIdx.x & (NPART - 1);
  if (tid < 128) {
    float s = 0;
    #pragma unroll
    for (int g = 0; g < 8; g++) s += red[g * 128 + tid];
    atomicAdd(&ys1[part * 128 + tid], s);
  } else {
    int cc = tid - 128;
    float s = 0;
    #pragma unroll
    for (int g = 0; g < 8; g++) s += red[1024 + g * 128 + cc];
    atomicAdd(&ys2[part * 128 + cc], s);
  }
}

// ---------------- aggregate (CSR, parity/uint2, fused node stats) ------------
// y entry (i, j) = u32 (bf16 mlp_j | bf16 scr_j<<16), j=0..63.
// Wave splits into 2 edge-parity groups (p=lane>>5); lane handles cols
// j0=2c, j1=2c+1 (c=lane&31) via one uint2 load per parity-edge. Parity
// partials merged with __shfl_xor(32). ys/as: [NPART][*] partials.

__global__ void aggregate_kernel(const u32* __restrict__ y, const int* __restrict__ row_ptr,
                                 const float* ys1, const float* ys2,
                                 const float* gm_l, const float* bem_l,
                                 const float* gs_l, const float* bes_l,
                                 float* __restrict__ agg, float* as1, float* as2) {
  __shared__ float aS[128], cS[128];
  __shared__ float ps[4][64], pq2[4][64];
  int tid = threadIdx.x;
  if (tid < 128) {
    float sA = 0, sB = 0;
    #pragma unroll
    for (int p = 0; p < NPART; p++) { sA += ys1[p * 128 + tid]; sB += ys2[p * 128 + tid]; }
    int cc = tid >> 1, scr = tid & 1;
    float mean = sA * (1.0f / M_EDGES);
    float var = sB * (1.0f / M_EDGES) - mean * mean;
    float g = scr ? gs_l[cc] : gm_l[cc];
    float b = scr ? bes_l[cc] : bem_l[cc];
    float av = g * rsqrtf(var + EPS);
    aS[tid] = av; cS[tid] = b - mean * av;
  }
  __syncthreads();
  int wv = tid >> 6, lane = tid & 63;
  int c = lane & 31, p = lane >> 5;
  // BN consts for cols j0=2c (aS[4c],aS[4c+1]) and j1=2c+1 (aS[4c+2],aS[4c+3])
  float am0 = aS[4 * c], cm0 = cS[4 * c];
  float as0 = aS[4 * c + 1], cs0 = cS[4 * c + 1];
  float am1 = aS[4 * c + 2], cm1 = cS[4 * c + 2];
  float as1v = aS[4 * c + 3], cs1 = cS[4 * c + 3];
  float sS0 = 0, sS1 = 0, sQ0 = 0, sQ1 = 0;
  #pragma unroll
  for (int k = 0; k < 4; k++) {
    int n = blockIdx.x * 16 + wv * 4 + k;
    int i0 = row_ptr[n], i1 = row_ptr[n + 1];
    float accA0 = 0, accA1 = 0, accB0 = 0, accB1 = 0;
    int i = i0 + p;
    for (; i + 2 < i1; i += 4) {
      uint2 wa = *(const uint2*)(y + (size_t)i * 64 + 2 * c);
      uint2 wb = *(const uint2*)(y + (size_t)(i + 2) * 64 + 2 * c);
      accA0 += sigmoidf_(fmaf(am0, bf2f((u16)wa.x), cm0)) *
               softplusf_(fmaf(as0, bf2f((u16)(wa.x >> 16)), cs0));
      accA1 += sigmoidf_(fmaf(am1, bf2f((u16)wa.y), cm1)) *
               softplusf_(fmaf(as1v, bf2f((u16)(wa.y >> 16)), cs1));
      accB0 += sigmoidf_(fmaf(am0, bf2f((u16)wb.x), cm0)) *
               softplusf_(fmaf(as0, bf2f((u16)(wb.x >> 16)), cs0));
      accB1 += sigmoidf_(fmaf(am1, bf2f((u16)wb.y), cm1)) *
               softplusf_(fmaf(as1v, bf2f((u16)(wb.y >> 16)), cs1));
    }
    if (i < i1) {
      uint2 wa = *(const uint2*)(y + (size_t)i * 64 + 2 * c);
      accA0 += sigmoidf_(fmaf(am0, bf2f((u16)wa.x), cm0)) *
               softplusf_(fmaf(as0, bf2f((u16)(wa.x >> 16)), cs0));
      accA1 += sigmoidf_(fmaf(am1, bf2f((u16)wa.y), cm1)) *
               softplusf_(fmaf(as1v, bf2f((u16)(wa.y >> 16)), cs1));
    }
    float acc0 = accA0 + accB0, acc1 = accA1 + accB1;
    acc0 += __shfl_xor(acc0, 32);
    acc1 += __shfl_xor(acc1, 32);
    if (p == 0) {
      *(float2*)&agg[(size_t)n * 64 + 2 * c] = make_float2(acc0, acc1);
      sS0 += acc0; sS1 += acc1;
      sQ0 += acc0 * acc0; sQ1 += acc1 * acc1;
    }
  }
  if (p == 0) {
    ps[wv][2 * c] = sS0; ps[wv][2 * c + 1] = sS1;
    pq2[wv][2 * c] = sQ0; pq2[wv][2 * c + 1] = sQ1;
  }
  __syncthreads();
  if (tid < 64) {
    float s = ps[0][tid] + ps[1][tid] + ps[2][tid] + ps[3][tid];
    float q = pq2[0][tid] + pq2[1][tid] + pq2[2][tid] + pq2[3][tid];
    int part = blockIdx.x & (NPART - 1);
    atomicAdd(&as1[part * 64 + tid], s);
    atomicAdd(&as2[part * 64 + tid], q);
  }
}

// plain node update (last layer); s1/s2 are [NPART][64] partials
__global__ void node_update_kernel(const float* agg, const float* s1, const float* s2,
                                   const float* gn_l, const float* ben_l, float* v) {
  __shared__ float aS[64], cS[64];
  int tid = threadIdx.x;
  if (tid < 64) {
    float sA = 0, sB = 0;
    #pragma unroll
    for (int p = 0; p < NPART; p++) { sA += s1[p * 64 + tid]; sB += s2[p * 64 + tid]; }
    float mean = sA * (1.0f / N_NODES);
    float var = sB * (1.0f / N_NODES) - mean * mean;
    float av = gn_l[tid] * rsqrtf(var + EPS);
    aS[tid] = av; cS[tid] = ben_l[tid] - mean * av;
  }
  __syncthreads();
  int idx = blockIdx.x * 256 + tid;  // N*64 exact
  int c = idx & 63;
  v[idx] = softplusf_(aS[c] * agg[idx] + cS[c] + v[idx]);
}

// ---------------- pooling + readout ----------------

__global__ void pool_sum_kernel(const float* v, const int* gid, float* psum, float* pcnt) {
  int tid = threadIdx.x;
  int g = blockIdx.x * 4 + (tid >> 6);
  int lane = tid & 63;
  int n0 = g * 64;
  if (n0 >= N_NODES) return;
  int n1 = min(n0 + 64, N_NODES);
  int cur = gid[n0];
  float acc = 0;
  int runlen = 0;
  for (int n = n0; n < n1; n++) {
    int gg = gid[n];
    if (gg != cur) {
      atomicAdd(&psum[cur * 64 + lane], acc);
      if (lane == 0) atomicAdd(&pcnt[cur], (float)runlen);
      acc = 0; runlen = 0; cur = gg;
    }
    acc += v[n * 64 + lane];
    runlen++;
  }
  atomicAdd(&psum[cur * 64 + lane], acc);
  if (lane == 0) atomicAdd(&pcnt[cur], (float)runlen);
}

__global__ void ro_mm1_kernel(const float* psum, const float* pcnt, const float* Wf0, float* y1) {
  int t = blockIdx.x * 256 + threadIdx.x;  // 256*32
  int row = t >> 5, q = t & 31;
  float inv = 1.0f / fmaxf(pcnt[row], 1.0f);
  float a0 = 0, a1 = 0, a2 = 0, a3 = 0;
  #pragma unroll 4
  for (int k = 0; k < 64; k++) {
    float x = psum[row * 64 + k] * inv;
    float4 w = *(const float4*)&Wf0[k * 128 + q * 4];
    a0 = fmaf(x, w.x, a0); a1 = fmaf(x, w.y, a1);
    a2 = fmaf(x, w.z, a2); a3 = fmaf(x, w.w, a3);
  }
  float4 r; r.x = a0; r.y = a1; r.z = a2; r.w = a3;
  *(float4*)&y1[row * 128 + q * 4] = r;
}

__global__ void ro_mm2_kernel(const float* y1, const float* gf0, const float* bef0,
                              const float* Wf1, float* y2) {
  __shared__ float aS[128], cS[128], pS[2][128], pQ[2][128];
  int tid = threadIdx.x;
  int c = tid & 127, h = tid >> 7;
  float s = 0, ss = 0;
  for (int rr = h * 128; rr < h * 128 + 128; rr++) {
    float x = y1[rr * 128 + c];
    s += x; ss += x * x;
  }
  pS[h][c] = s; pQ[h][c] = ss;
  __syncthreads();
  if (tid < 128) {
    float S = pS[0][tid] + pS[1][tid], Q = pQ[0][tid] + pQ[1][tid];
    float mean = S * (1.0f / 256.0f), var = Q * (1.0f / 256.0f) - mean * mean;
    float av = gf0[tid] * rsqrtf(var + EPS);
    aS[tid] = av; cS[tid] = bef0[tid] - mean * av;
  }
  __syncthreads();
  int t = blockIdx.x * 256 + tid;  // 256*16
  int row = t >> 4, q = t & 15;
  float a0 = 0, a1 = 0, a2 = 0, a3 = 0;
  #pragma unroll 4
  for (int k = 0; k < 128; k++) {
    float act = siluf_(fmaf(aS[k], y1[row * 128 + k], cS[k]));
    float4 w = *(const float4*)&Wf1[k * 64 + q * 4];
    a0 = fmaf(act, w.x, a0); a1 = fmaf(act, w.y, a1);
    a2 = fmaf(act, w.z, a2); a3 = fmaf(act, w.w, a3);
  }
  float4 r; r.x = a0; r.y = a1; r.z = a2; r.w = a3;
  *(float4*)&y2[row * 64 + q * 4] = r;
}

__global__ void ro_out_kernel(const float* y2, const float* gf1, const float* bef1,
                              const float* Wt, const float* bt, float* out) {
  __shared__ float aS[64], cS[64], pS[4][64], pQ[4][64];
  int tid = threadIdx.x;
  int c = tid & 63, h = tid >> 6;
  float s = 0, ss = 0;
  for (int rr = h * 64; rr < h * 64 + 64; rr++) {
    float x = y2[rr * 64 + c];
    s += x; ss += x * x;
  }
  pS[h][c] = s; pQ[h][c] = ss;
  __syncthreads();
  if (tid < 64) {
    float S = pS[0][tid] + pS[1][tid] + pS[2][tid] + pS[3][tid];
    float Q = pQ[0][tid] + pQ[1][tid] + pQ[2][tid] + pQ[3][tid];
    float mean = S * (1.0f / 256.0f), var = Q * (1.0f / 256.0f) - mean * mean;
    float av = gf1[tid] * rsqrtf(var + EPS);
    aS[tid] = av; cS[tid] = bef1[tid] - mean * av;
  }
  __syncthreads();
  float acc = bt[0];
  #pragma unroll 4
  for (int cc = 0; cc < 64; cc++)
    acc += siluf_(fmaf(aS[cc], y2[tid * 64 + cc], cS[cc])) * Wt[cc];
  out[tid] = acc;
}

// ---------------- host ----------------

extern "C" void kernel_launch(void* const* d_in, const int* in_sizes, int n_in,
                              void* d_out, int out_size, void* d_ws, size_t ws_size,
                              hipStream_t stream) {
  const float* node_feats = (const float*)d_in[0];
  const float* edge_feats = (const float*)d_in[1];
  const int* src = (const int*)d_in[2];
  const int* dst = (const int*)d_in[3];
  const int* gid = (const int*)d_in[4];
  const float* W_emb = (const float*)d_in[5];
  const float* g_emb = (const float*)d_in[7];
  const float* be_emb = (const float*)d_in[8];
  const float* Wm = (const float*)d_in[9];
  const float* gm = (const float*)d_in[11];
  const float* bem = (const float*)d_in[12];
  const float* Wsc = (const float*)d_in[13];
  const float* gs = (const float*)d_in[15];
  const float* bes = (const float*)d_in[16];
  const float* gn = (const float*)d_in[17];
  const float* ben = (const float*)d_in[18];
  const float* Wf0 = (const float*)d_in[19];
  const float* gf0 = (const float*)d_in[21];
  const float* bef0 = (const float*)d_in[22];
  const float* Wf1 = (const float*)d_in[23];
  const float* gf1 = (const float*)d_in[25];
  const float* bef1 = (const float*)d_in[26];
  const float* Wt = (const float*)d_in[27];
  const float* bt = (const float*)d_in[28];
  float* out = (float*)d_out;

  char* ws = (char*)d_ws;
  size_t off = 0;
  auto alloc = [&](size_t bytes) -> void* {
    void* p = ws + off;
    off = (off + bytes + 511) & ~(size_t)511;
    return p;
  };
  u16* ef_s   = (u16*)alloc((size_t)M_EDGES * 48 * 2);   // padded, bf16
  u32* ybuf   = (u32*)alloc((size_t)M_EDGES * 64 * 4);   // interleaved (mlp|scr) pairs
  u16* Ptop   = (u16*)alloc((size_t)N_NODES * 128 * 2);  // interleaved bf16 tables
  u16* Pmid   = (u16*)alloc((size_t)N_NODES * 128 * 2);
  float* vbuf = (float*)alloc((size_t)N_NODES * 64 * 4);
  float* nbuf = (float*)alloc((size_t)N_NODES * 64 * 4);
  int* row_ptr = (int*)alloc((size_t)(N_NODES + 1) * 4);
  int* nexts   = (int*)alloc((size_t)N_NODES * 4);
  int* eid_s   = (int*)alloc((size_t)M_EDGES * 4);
  int* src_s   = (int*)alloc((size_t)M_EDGES * 4);
  int* dst_s   = (int*)alloc((size_t)M_EDGES * 4);
  int* bsum    = (int*)alloc(256 * 4);
  int* boffs   = (int*)alloc(256 * 4);
  float* stats = (float*)alloc((size_t)80000 * 4);
  (void)ws_size; (void)in_sizes; (void)n_in; (void)out_size;

  // stats region layout (floats); [0, 26880) zeroed each call
  float* emb_p1 = stats + 0;       // [8][64]
  float* emb_p2 = stats + 512;     // [8][64]
  float* ys_p1  = stats + 1024;    // NL x [8][128]
  float* ys_p2  = stats + 4096;    // NL x [8][128]
  float* as_p1  = stats + 7168;    // NL x [8][64]
  float* as_p2  = stats + 8704;    // NL x [8][64]
  float* pcnt   = stats + 10240;   // 256
  float* psum   = stats + 10496;   // 256*64 -> ends 26880
  float* rb1    = stats + 26880;   // 256*128
  float* rb2    = stats + 59648;   // 256*64 -> ends 76032

  // preprocessing
  zero_kernel<<<196, 256, 0, stream>>>(nexts, stats, N_NODES, 26880);
  hist_kernel<<<3125, 256, 0, stream>>>(dst, nexts);
  scanA_kernel<<<196, 256, 0, stream>>>(nexts, bsum);
  scanB_kernel<<<1, 256, 0, stream>>>(bsum, boffs, row_ptr);
  scanC_kernel<<<196, 256, 0, stream>>>(nexts, boffs, row_ptr, nexts);
  scatter_kernel<<<3125, 256, 0, stream>>>(src, dst, nexts, eid_s);
  permute_ef_kernel<<<25000, 256, 0, stream>>>(edge_feats, eid_s, src, dst,
                                               ef_s, src_s, dst_s);

  // embedding (stats fused, 8-slot partials)
  emb_mm_kernel<<<3125, 256, 0, stream>>>(node_feats, W_emb, nbuf, emb_p1, emb_p2);
  finv_ptab_kernel<<<782, 256, 0, stream>>>(nbuf, vbuf, emb_p1, emb_p2, g_emb, be_emb,
                                            Wm, Wsc, Ptop, Pmid, 1.0f / N_NODES, 0);

  for (int l = 0; l < NL; l++) {
    const float* Wm_l = Wm + (size_t)l * 169 * 64;
    const float* Ws_l = Wsc + (size_t)l * 169 * 64;
    edge_mm_kernel<<<1250, 256, 0, stream>>>(src_s, dst_s, ef_s, Ptop, Pmid,
                                             Wm_l, Ws_l, ybuf,
                                             ys_p1 + l * 1024, ys_p2 + l * 1024);
    aggregate_kernel<<<3125, 256, 0, stream>>>(ybuf, row_ptr,
                                               ys_p1 + l * 1024, ys_p2 + l * 1024,
                                               gm + l * 64, bem + l * 64,
                                               gs + l * 64, bes + l * 64, nbuf,
                                               as_p1 + l * 512, as_p2 + l * 512);
    if (l < NL - 1) {
      finv_ptab_kernel<<<782, 256, 0, stream>>>(nbuf, vbuf,
                                                as_p1 + l * 512, as_p2 + l * 512,
                                                gn + l * 64, ben + l * 64,
                                                Wm + (size_t)(l + 1) * 169 * 64,
                                                Wsc + (size_t)(l + 1) * 169 * 64,
                                                Ptop, Pmid, 1.0f / N_NODES, 1);
    } else {
      node_update_kernel<<<12500, 256, 0, stream>>>(nbuf,
                                                    as_p1 + l * 512, as_p2 + l * 512,
                                                    gn + l * 64, ben + l * 64, vbuf);
    }
  }

  // pooling + readout
  pool_sum_kernel<<<196, 256, 0, stream>>>(vbuf, gid, psum, pcnt);
  ro_mm1_kernel<<<32, 256, 0, stream>>>(psum, pcnt, Wf0, rb1);
  ro_mm2_kernel<<<16, 256, 0, stream>>>(rb1, gf0, bef0, Wf1, rb2);
  ro_out_kernel<<<1, 256, 0, stream>>>(rb2, gf1, bef1, Wt, bt, out);
}

// Round 14
// 1092.284 us; speedup vs baseline: 1.0965x; 1.0482x over previous
//
#include <hip/hip_runtime.h>
#include <stdint.h>

// CGCNN forward, round 14:
//  - edge_mm: persistent grid of 512 blocks (= exactly 2 blocks/CU capacity,
//    the measured traffic-optimal concurrency). Each block owns a contiguous
//    chunk of 12-13 tiles (6250 total): grid-drain tail 2.44-fills->~6%
//    imbalance, W-staging amortized 5->12 tiles.
//  - last layer: node_update fused into pool_sum (v computed on the fly,
//    never materialized): -25 MB traffic, -1 launch.
// Biases before BN cancel exactly -> skipped.

#define N_NODES 50000
#define M_EDGES 800000
#define FV 92
#define FE 41
#define EMB 64
#define NL 3
#define EPS 1e-5f
#define NPART 8

typedef unsigned short u16;
typedef unsigned int u32;
typedef __attribute__((ext_vector_type(8))) short bf16x8;
typedef __attribute__((ext_vector_type(16))) float f32x16;

__device__ __forceinline__ float bf2f(u16 u) {
  return __uint_as_float(((u32)u) << 16);
}
__device__ __forceinline__ u16 f2bf(float f) {
  u32 x = __float_as_uint(f);
  return (u16)((x + 0x7fffu + ((x >> 16) & 1u)) >> 16);
}
__device__ __forceinline__ float sigmoidf_(float x) { return 1.0f / (1.0f + __expf(-x)); }
__device__ __forceinline__ float softplusf_(float x) {
  return fmaxf(x, 0.f) + __logf(1.f + __expf(-fabsf(x)));
}
__device__ __forceinline__ float siluf_(float x) { return x * sigmoidf_(x); }

// ---------------- preprocessing ----------------

__global__ void zero_kernel(int* nexts, float* stats, int nInts, int nFloats) {
  int i = blockIdx.x * 256 + threadIdx.x;
  if (i < nInts) nexts[i] = 0;
  if (i < nFloats) stats[i] = 0.f;
}

__global__ void hist_kernel(const int* dst, int* hist) {
  int e = blockIdx.x * 256 + threadIdx.x;
  if (e < M_EDGES) atomicAdd(&hist[dst[e]], 1);
}

__global__ void scanA_kernel(const int* hist, int* bsum) {
  int tid = threadIdx.x;
  int i = blockIdx.x * 256 + tid;
  int x = (i < N_NODES) ? hist[i] : 0;
  #pragma unroll
  for (int o = 32; o > 0; o >>= 1) x += __shfl_xor(x, o);
  __shared__ int wsm[4];
  if ((tid & 63) == 0) wsm[tid >> 6] = x;
  __syncthreads();
  if (tid == 0) bsum[blockIdx.x] = wsm[0] + wsm[1] + wsm[2] + wsm[3];
}

__global__ void scanB_kernel(const int* bsum, int* boffs, int* row_ptr) {
  int tid = threadIdx.x;
  int lane = tid & 63, wid = tid >> 6;
  int x = (tid < 196) ? bsum[tid] : 0;
  int v = x;
  #pragma unroll
  for (int o = 1; o < 64; o <<= 1) {
    int nv = __shfl_up(v, o);
    if (lane >= o) v += nv;
  }
  __shared__ int wsm[4];
  if (lane == 63) wsm[wid] = v;
  __syncthreads();
  int add = 0;
  for (int wq = 0; wq < wid; wq++) add += wsm[wq];
  if (tid < 196) boffs[tid] = v + add - x;  // exclusive
  if (tid == 0) row_ptr[N_NODES] = M_EDGES;
}

__global__ void scanC_kernel(const int* hist, const int* boffs, int* row_ptr, int* nexts) {
  int tid = threadIdx.x;
  int i = blockIdx.x * 256 + tid;
  int lane = tid & 63, wid = tid >> 6;
  int x = (i < N_NODES) ? hist[i] : 0;
  int v = x;
  #pragma unroll
  for (int o = 1; o < 64; o <<= 1) {
    int nv = __shfl_up(v, o);
    if (lane >= o) v += nv;
  }
  __shared__ int wsm[4];
  if (lane == 63) wsm[wid] = v;
  __syncthreads();
  int add = boffs[blockIdx.x];
  for (int wq = 0; wq < wid; wq++) add += wsm[wq];
  int excl = v - x + add;
  if (i < N_NODES) { row_ptr[i] = excl; nexts[i] = excl; }
}

__global__ void scatter_kernel(const int* src, const int* dst, int* nexts, int* eid_s) {
  int e = blockIdx.x * 256 + threadIdx.x;
  if (e < M_EDGES) {
    int p = atomicAdd(&nexts[dst[e]], 1);
    eid_s[p] = e;
  }
}

// gather-direction permute (coalesced writes, zero-padded 48 cols) +
// materialize src_s/dst_s (random L2 reads, coalesced writes)
__global__ void permute_ef_kernel(const float* ef, const int* eid_s,
                                  const int* src, const int* dst,
                                  u16* ef_s, int* src_s, int* dst_s) {
  int tid = threadIdx.x;
  u32 p = blockIdx.x * 32 + (tid >> 3);  // 25000 blocks * 32 rows = M
  int q = tid & 7;
  int e = eid_s[p];
  if (q == 0) { src_s[p] = src[e]; dst_s[p] = dst[e]; }
  const float* base = ef + (size_t)e * 41;
  u32* orow = (u32*)ef_s + (size_t)p * 24 + q * 3;
  #pragma unroll
  for (int i = 0; i < 3; i++) {
    int k = q * 6 + i * 2;
    float lo = (k < 41) ? base[k] : 0.f;
    float hi = (k + 1 < 41) ? base[k + 1] : 0.f;
    orow[i] = (u32)f2bf(lo) | ((u32)f2bf(hi) << 16);
  }
}

// ---------------- embedding (matmul + fused column stats, 8-slot partials) ---

__global__ void emb_mm_kernel(const float* nf, const float* Wemb, float* y0,
                              float* s1, float* s2) {
  __shared__ float Wl[FV][EMB];          // 23.5 KB
  __shared__ float ps[16][64], pq2[16][64];  // 8 KB
  int tid = threadIdx.x;
  for (int idx = tid; idx < FV * EMB; idx += 256) Wl[idx >> 6][idx & 63] = Wemb[idx];
  __syncthreads();
  int t = blockIdx.x * 256 + tid;  // N*16
  int n = t >> 4, q = t & 15;
  const float* row = nf + n * FV;
  float a0 = 0, a1 = 0, a2 = 0, a3 = 0;
  #pragma unroll 4
  for (int k = 0; k < FV; k++) {
    float x = row[k];
    float4 w = *(const float4*)&Wl[k][q * 4];
    a0 = fmaf(x, w.x, a0); a1 = fmaf(x, w.y, a1);
    a2 = fmaf(x, w.z, a2); a3 = fmaf(x, w.w, a3);
  }
  float4 r; r.x = a0; r.y = a1; r.z = a2; r.w = a3;
  *(float4*)&y0[n * EMB + q * 4] = r;
  int nl = tid >> 4, q4 = (tid & 15) * 4;
  ps[nl][q4] = a0; ps[nl][q4 + 1] = a1; ps[nl][q4 + 2] = a2; ps[nl][q4 + 3] = a3;
  pq2[nl][q4] = a0 * a0; pq2[nl][q4 + 1] = a1 * a1;
  pq2[nl][q4 + 2] = a2 * a2; pq2[nl][q4 + 3] = a3 * a3;
  __syncthreads();
  if (tid < 64) {
    float s = 0, ss = 0;
    #pragma unroll
    for (int g = 0; g < 16; g++) { s += ps[g][tid]; ss += pq2[g][tid]; }
    int part = blockIdx.x & (NPART - 1);
    atomicAdd(&s1[part * 64 + tid], s);
    atomicAdd(&s2[part * 64 + tid], ss);
  }
}

// ---------------- fused BN-finalize + v activation + P tables (MFMA) --------
// mode 0: v = silu(bn(X)); mode 1: v = softplus(bn(X)+v). Then P = v @ W
// halves via mfma_32x32x16_bf16. 64 nodes/block, grid 782 (tail guarded).

__global__ __launch_bounds__(256) void finv_ptab_kernel(
    const float* __restrict__ X, float* __restrict__ vio,
    const float* s1, const float* s2, const float* g, const float* be,
    const float* __restrict__ Wm_l, const float* __restrict__ Ws_l,
    u16* __restrict__ Ptop, u16* __restrict__ Pmid, float minv, int mode) {
  __shared__ u16 vls[64 * 64];   // 8 KB
  __shared__ u16 WbF[16384];     // 32 KB: [mat][cg][ks][lane]*8
  __shared__ float aS[64], cS[64];
  int tid = threadIdx.x;
  if (tid < 64) {
    float sA = 0, sB = 0;
    #pragma unroll
    for (int p = 0; p < NPART; p++) { sA += s1[p * 64 + tid]; sB += s2[p * 64 + tid]; }
    float mean = sA * minv;
    float var = sB * minv - mean * mean;
    float av = g[tid] * rsqrtf(var + EPS);
    aS[tid] = av; cS[tid] = be[tid] - mean * av;
  }
  __syncthreads();
  int nb = blockIdx.x * 64;
  #pragma unroll
  for (int it = 0; it < 16; it++) {
    int idx = it * 256 + tid;
    int nl = idx >> 6, c = idx & 63;
    int n = nb + nl;
    float vn = 0.f;
    if (n < N_NODES) {
      size_t gi = (size_t)n * 64 + c;
      float z = fmaf(aS[c], X[gi], cS[c]);
      vn = mode ? softplusf_(z + vio[gi]) : siluf_(z);
      vio[gi] = vn;
    }
    vls[nl * 64 + (c ^ ((nl & 7) << 3))] = f2bf(vn);
  }
  for (int t = tid; t < 16384; t += 256) {
    int slot = t >> 3, j = t & 7;
    int mat = slot >> 10;
    int rem = slot & 1023;
    int cg = rem >> 8;
    int rem2 = rem & 255;
    int ks = rem2 >> 6, ln = rem2 & 63;
    int ic = cg * 32 + (ln & 31);
    int feat = ic >> 1, scr = ic & 1;
    int k = ks * 16 + ((ln >> 5) << 3) + j;
    int wrow = mat * 64 + k;
    float val = scr ? Ws_l[wrow * 64 + feat] : Wm_l[wrow * 64 + feat];
    WbF[t] = f2bf(val);
  }
  __syncthreads();
  int wv = tid >> 6, lane = tid & 63, l31 = lane & 31, lh = lane >> 5;
  int st = wv >> 1;       // node subtile (32 nodes)
  int mat = wv & 1;       // 0: Ptop, 1: Pmid
  bf16x8 afr[4];
  #pragma unroll
  for (int ks = 0; ks < 4; ks++) {
    int row = st * 32 + l31;
    afr[ks] = *(const bf16x8*)&vls[row * 64 + ((ks * 16 + lh * 8) ^ ((row & 7) << 3))];
  }
  u16* Pt = mat ? Pmid : Ptop;
  #pragma unroll
  for (int cg = 0; cg < 4; cg++) {
    f32x16 acc;
    #pragma unroll
    for (int i = 0; i < 16; i++) acc[i] = 0.f;
    #pragma unroll
    for (int ks = 0; ks < 4; ks++) {
      bf16x8 b = *(const bf16x8*)&WbF[(((mat * 4 + cg) * 4 + ks) * 64 + lane) * 8];
      acc = __builtin_amdgcn_mfma_f32_32x32x16_bf16(afr[ks], b, acc, 0, 0, 0);
    }
    #pragma unroll
    for (int rg = 0; rg < 16; rg++) {
      int row = (rg & 3) + 8 * (rg >> 2) + 4 * lh;  // C/D layout (m74/m101)
      int node = nb + st * 32 + row;
      if (node < N_NODES)
        Pt[(size_t)node * 128 + cg * 32 + l31] = f2bf(acc[rg]);
    }
  }
}

// ---------------- MFMA edge kernel (persistent 512 blocks) -------------------
// 512 blocks (exactly 2/CU capacity, measured traffic-optimal concurrency);
// block b owns a contiguous chunk of 12-13 of the 6250 tiles (128 edges each).
// Batched epilogue: all index loads -> all 32 row-gathers -> compute. B cols
// permuted so lane l's acc quad = (mlp_2c, scr_2c, mlp_{2c+1}, scr_{2c+1}),
// c=l&31; C/D row = (rg&3)+8*(rg>>2)+4*(l>>5).
__global__ __launch_bounds__(256, 2) void edge_mm_kernel(
    const int* __restrict__ src_s, const int* __restrict__ dst_s,
    const u16* __restrict__ ef_s,
    const u16* __restrict__ Ptop, const u16* __restrict__ Pmid,
    const float* __restrict__ Wm_l, const float* __restrict__ Ws_l,
    u32* __restrict__ y, float* __restrict__ ys1, float* __restrict__ ys2) {
  __shared__ u16 WbF[6144];      // B frags, 12 KB
  __shared__ float red[2048];    // stats reduce, 8 KB
  int tid = threadIdx.x;
  int w = tid >> 6, lane = tid & 63;
  int l31 = lane & 31, lh = lane >> 5;

  // XCD swizzle (512 = 8*64, exactly divisible): contiguous tile chunks per XCD
  int bswz = (blockIdx.x & 7) * 64 + (blockIdx.x >> 3);

  // contiguous tile chunk: 6250 = 512*12 + 106
  int tstart = bswz * 12 + min(bswz, 106);
  int tcnt = 12 + (bswz < 106 ? 1 : 0);

  // stage Wbot as B fragments with column permutation:
  // p = tt*32 + l -> feature col 2l+(tt>>1), half = tt&1 (0:mlp W, 1:scr W)
  for (int t = tid; t < 6144; t += 256) {
    int slot = t >> 3, j = t & 7;
    int tt = slot / 192, rem = slot - tt * 192;
    int ks = rem >> 6, ln = rem & 63;
    int c = 2 * (ln & 31) + (tt >> 1);
    int k = ks * 16 + ((ln >> 5) << 3) + j;
    float val = 0.f;
    if (k < FE) val = (tt & 1) ? Ws_l[(128 + k) * 64 + c] : Wm_l[(128 + k) * 64 + c];
    WbF[t] = f2bf(val);
  }
  __syncthreads();

  float sum4[4] = {0, 0, 0, 0}, ssq4[4] = {0, 0, 0, 0};

  for (int tile = 0; tile < tcnt; tile++) {
    int T = (tstart + tile) * 128;
    const u16* ap = ef_s + (size_t)(T + 32 * w + l31) * 48 + lh * 8;
    bf16x8 a0 = *(const bf16x8*)(ap);
    bf16x8 a1 = *(const bf16x8*)(ap + 16);
    bf16x8 a2 = *(const bf16x8*)(ap + 32);
    f32x16 acc0, acc1, acc2, acc3;
    #pragma unroll
    for (int i = 0; i < 16; i++) { acc0[i] = 0.f; acc1[i] = 0.f; acc2[i] = 0.f; acc3[i] = 0.f; }
    #pragma unroll
    for (int ks = 0; ks < 3; ks++) {
      bf16x8 a = (ks == 0) ? a0 : (ks == 1) ? a1 : a2;
      bf16x8 b0 = *(const bf16x8*)&WbF[((0 * 3 + ks) * 64 + lane) * 8];
      bf16x8 b1 = *(const bf16x8*)&WbF[((1 * 3 + ks) * 64 + lane) * 8];
      bf16x8 b2 = *(const bf16x8*)&WbF[((2 * 3 + ks) * 64 + lane) * 8];
      bf16x8 b3 = *(const bf16x8*)&WbF[((3 * 3 + ks) * 64 + lane) * 8];
      acc0 = __builtin_amdgcn_mfma_f32_32x32x16_bf16(a, b0, acc0, 0, 0, 0);
      acc1 = __builtin_amdgcn_mfma_f32_32x32x16_bf16(a, b1, acc1, 0, 0, 0);
      acc2 = __builtin_amdgcn_mfma_f32_32x32x16_bf16(a, b2, acc2, 0, 0, 0);
      acc3 = __builtin_amdgcn_mfma_f32_32x32x16_bf16(a, b3, acc3, 0, 0, 0);
    }
    // batched epilogue: indices -> gathers -> compute
    int sv[16], dv[16];
    #pragma unroll
    for (int rg = 0; rg < 16; rg++) {
      int row = (rg & 3) + 8 * (rg >> 2) + 4 * lh;  // C/D layout (m74/m101)
      int i = T + 32 * w + row;
      sv[rg] = src_s[i];
      dv[rg] = dst_s[i];
    }
    uint2 ptv[16], pmv[16];
    #pragma unroll
    for (int rg = 0; rg < 16; rg++)
      ptv[rg] = *(const uint2*)((const u32*)Ptop + (size_t)sv[rg] * 64 + 2 * l31);
    #pragma unroll
    for (int rg = 0; rg < 16; rg++)
      pmv[rg] = *(const uint2*)((const u32*)Pmid + (size_t)dv[rg] * 64 + 2 * l31);
    #pragma unroll
    for (int rg = 0; rg < 16; rg++) {
      int row = (rg & 3) + 8 * (rg >> 2) + 4 * lh;
      int i = T + 32 * w + row;
      float ym0 = acc0[rg] + bf2f((u16)ptv[rg].x) + bf2f((u16)pmv[rg].x);
      float ysv0 = acc1[rg] + bf2f((u16)(ptv[rg].x >> 16)) + bf2f((u16)(pmv[rg].x >> 16));
      float ym1 = acc2[rg] + bf2f((u16)ptv[rg].y) + bf2f((u16)pmv[rg].y);
      float ysv1 = acc3[rg] + bf2f((u16)(ptv[rg].y >> 16)) + bf2f((u16)(pmv[rg].y >> 16));
      ((ushort4*)y)[(size_t)i * 32 + l31] =
          make_ushort4(f2bf(ym0), f2bf(ysv0), f2bf(ym1), f2bf(ysv1));
      sum4[0] += ym0; sum4[1] += ysv0; sum4[2] += ym1; sum4[3] += ysv1;
      ssq4[0] += ym0 * ym0; ssq4[1] += ysv0 * ysv0;
      ssq4[2] += ym1 * ym1; ssq4[3] += ysv1 * ysv1;
    }
  }
  // block-reduce stats in interleaved col space ic = 4*l31 + j
  __syncthreads();
  int slotw = w * 2 + lh;  // 8 groups of 32 lanes, each holds 4 cols
  #pragma unroll
  for (int j = 0; j < 4; j++) {
    red[slotw * 128 + l31 * 4 + j] = sum4[j];
    red[1024 + slotw * 128 + l31 * 4 + j] = ssq4[j];
  }
  __syncthreads();
  int part = blockIdx.x & (NPART - 1);
  if (tid < 128) {
    float s = 0;
    #pragma unroll
    for (int g = 0; g < 8; g++) s += red[g * 128 + tid];
    atomicAdd(&ys1[part * 128 + tid], s);
  } else {
    int cc = tid - 128;
    float s = 0;
    #pragma unroll
    for (int g = 0; g < 8; g++) s += red[1024 + g * 128 + cc];
    atomicAdd(&ys2[part * 128 + cc], s);
  }
}

// ---------------- aggregate (CSR, parity/uint2, fused node stats) ------------

__global__ void aggregate_kernel(const u32* __restrict__ y, const int* __restrict__ row_ptr,
                                 const float* ys1, const float* ys2,
                                 const float* gm_l, const float* bem_l,
                                 const float* gs_l, const float* bes_l,
                                 float* __restrict__ agg, float* as1, float* as2) {
  __shared__ float aS[128], cS[128];
  __shared__ float ps[4][64], pq2[4][64];
  int tid = threadIdx.x;
  if (tid < 128) {
    float sA = 0, sB = 0;
    #pragma unroll
    for (int p = 0; p < NPART; p++) { sA += ys1[p * 128 + tid]; sB += ys2[p * 128 + tid]; }
    int cc = tid >> 1, scr = tid & 1;
    float mean = sA * (1.0f / M_EDGES);
    float var = sB * (1.0f / M_EDGES) - mean * mean;
    float g = scr ? gs_l[cc] : gm_l[cc];
    float b = scr ? bes_l[cc] : bem_l[cc];
    float av = g * rsqrtf(var + EPS);
    aS[tid] = av; cS[tid] = b - mean * av;
  }
  __syncthreads();
  int wv = tid >> 6, lane = tid & 63;
  int c = lane & 31, p = lane >> 5;
  float am0 = aS[4 * c], cm0 = cS[4 * c];
  float as0 = aS[4 * c + 1], cs0 = cS[4 * c + 1];
  float am1 = aS[4 * c + 2], cm1 = cS[4 * c + 2];
  float as1v = aS[4 * c + 3], cs1 = cS[4 * c + 3];
  float sS0 = 0, sS1 = 0, sQ0 = 0, sQ1 = 0;
  #pragma unroll
  for (int k = 0; k < 4; k++) {
    int n = blockIdx.x * 16 + wv * 4 + k;
    int i0 = row_ptr[n], i1 = row_ptr[n + 1];
    float accA0 = 0, accA1 = 0, accB0 = 0, accB1 = 0;
    int i = i0 + p;
    for (; i + 2 < i1; i += 4) {
      uint2 wa = *(const uint2*)(y + (size_t)i * 64 + 2 * c);
      uint2 wb = *(const uint2*)(y + (size_t)(i + 2) * 64 + 2 * c);
      accA0 += sigmoidf_(fmaf(am0, bf2f((u16)wa.x), cm0)) *
               softplusf_(fmaf(as0, bf2f((u16)(wa.x >> 16)), cs0));
      accA1 += sigmoidf_(fmaf(am1, bf2f((u16)wa.y), cm1)) *
               softplusf_(fmaf(as1v, bf2f((u16)(wa.y >> 16)), cs1));
      accB0 += sigmoidf_(fmaf(am0, bf2f((u16)wb.x), cm0)) *
               softplusf_(fmaf(as0, bf2f((u16)(wb.x >> 16)), cs0));
      accB1 += sigmoidf_(fmaf(am1, bf2f((u16)wb.y), cm1)) *
               softplusf_(fmaf(as1v, bf2f((u16)(wb.y >> 16)), cs1));
    }
    if (i < i1) {
      uint2 wa = *(const uint2*)(y + (size_t)i * 64 + 2 * c);
      accA0 += sigmoidf_(fmaf(am0, bf2f((u16)wa.x), cm0)) *
               softplusf_(fmaf(as0, bf2f((u16)(wa.x >> 16)), cs0));
      accA1 += sigmoidf_(fmaf(am1, bf2f((u16)wa.y), cm1)) *
               softplusf_(fmaf(as1v, bf2f((u16)(wa.y >> 16)), cs1));
    }
    float acc0 = accA0 + accB0, acc1 = accA1 + accB1;
    acc0 += __shfl_xor(acc0, 32);
    acc1 += __shfl_xor(acc1, 32);
    if (p == 0) {
      *(float2*)&agg[(size_t)n * 64 + 2 * c] = make_float2(acc0, acc1);
      sS0 += acc0; sS1 += acc1;
      sQ0 += acc0 * acc0; sQ1 += acc1 * acc1;
    }
  }
  if (p == 0) {
    ps[wv][2 * c] = sS0; ps[wv][2 * c + 1] = sS1;
    pq2[wv][2 * c] = sQ0; pq2[wv][2 * c + 1] = sQ1;
  }
  __syncthreads();
  if (tid < 64) {
    float s = ps[0][tid] + ps[1][tid] + ps[2][tid] + ps[3][tid];
    float q = pq2[0][tid] + pq2[1][tid] + pq2[2][tid] + pq2[3][tid];
    int part = blockIdx.x & (NPART - 1);
    atomicAdd(&as1[part * 64 + tid], s);
    atomicAdd(&as2[part * 64 + tid], q);
  }
}

// ---------------- fused last-layer node update + pooling ---------------------
// v = softplus(bn(agg)+vprev) computed on the fly (never stored); gid-sorted
// run-length accumulation into psum/pcnt. 196 blocks x 4 waves x 64 nodes.
__global__ void node_pool_kernel(const float* __restrict__ agg,
                                 const float* __restrict__ vprev,
                                 const float* s1, const float* s2,
                                 const float* gn_l, const float* ben_l,
                                 const int* __restrict__ gid,
                                 float* psum, float* pcnt) {
  __shared__ float aS[64], cS[64];
  int tid = threadIdx.x;
  if (tid < 64) {
    float sA = 0, sB = 0;
    #pragma unroll
    for (int p = 0; p < NPART; p++) { sA += s1[p * 64 + tid]; sB += s2[p * 64 + tid]; }
    float mean = sA * (1.0f / N_NODES);
    float var = sB * (1.0f / N_NODES) - mean * mean;
    float av = gn_l[tid] * rsqrtf(var + EPS);
    aS[tid] = av; cS[tid] = ben_l[tid] - mean * av;
  }
  __syncthreads();
  int g = blockIdx.x * 4 + (tid >> 6);
  int lane = tid & 63;
  int n0 = g * 64;
  if (n0 >= N_NODES) return;
  int n1 = min(n0 + 64, N_NODES);
  float a = aS[lane], cc = cS[lane];
  int cur = gid[n0];
  float acc = 0;
  int runlen = 0;
  for (int n = n0; n < n1; n++) {
    int gg = gid[n];
    if (gg != cur) {
      atomicAdd(&psum[cur * 64 + lane], acc);
      if (lane == 0) atomicAdd(&pcnt[cur], (float)runlen);
      acc = 0; runlen = 0; cur = gg;
    }
    size_t gi = (size_t)n * 64 + lane;
    acc += softplusf_(fmaf(a, agg[gi], cc) + vprev[gi]);
    runlen++;
  }
  atomicAdd(&psum[cur * 64 + lane], acc);
  if (lane == 0) atomicAdd(&pcnt[cur], (float)runlen);
}

// ---------------- readout ----------------

__global__ void ro_mm1_kernel(const float* psum, const float* pcnt, const float* Wf0, float* y1) {
  int t = blockIdx.x * 256 + threadIdx.x;  // 256*32
  int row = t >> 5, q = t & 31;
  float inv = 1.0f / fmaxf(pcnt[row], 1.0f);
  float a0 = 0, a1 = 0, a2 = 0, a3 = 0;
  #pragma unroll 4
  for (int k = 0; k < 64; k++) {
    float x = psum[row * 64 + k] * inv;
    float4 w = *(const float4*)&Wf0[k * 128 + q * 4];
    a0 = fmaf(x, w.x, a0); a1 = fmaf(x, w.y, a1);
    a2 = fmaf(x, w.z, a2); a3 = fmaf(x, w.w, a3);
  }
  float4 r; r.x = a0; r.y = a1; r.z = a2; r.w = a3;
  *(float4*)&y1[row * 128 + q * 4] = r;
}

__global__ void ro_mm2_kernel(const float* y1, const float* gf0, const float* bef0,
                              const float* Wf1, float* y2) {
  __shared__ float aS[128], cS[128], pS[2][128], pQ[2][128];
  int tid = threadIdx.x;
  int c = tid & 127, h = tid >> 7;
  float s = 0, ss = 0;
  for (int rr = h * 128; rr < h * 128 + 128; rr++) {
    float x = y1[rr * 128 + c];
    s += x; ss += x * x;
  }
  pS[h][c] = s; pQ[h][c] = ss;
  __syncthreads();
  if (tid < 128) {
    float S = pS[0][tid] + pS[1][tid], Q = pQ[0][tid] + pQ[1][tid];
    float mean = S * (1.0f / 256.0f), var = Q * (1.0f / 256.0f) - mean * mean;
    float av = gf0[tid] * rsqrtf(var + EPS);
    aS[tid] = av; cS[tid] = bef0[tid] - mean * av;
  }
  __syncthreads();
  int t = blockIdx.x * 256 + tid;  // 256*16
  int row = t >> 4, q = t & 15;
  float a0 = 0, a1 = 0, a2 = 0, a3 = 0;
  #pragma unroll 4
  for (int k = 0; k < 128; k++) {
    float act = siluf_(fmaf(aS[k], y1[row * 128 + k], cS[k]));
    float4 w = *(const float4*)&Wf1[k * 64 + q * 4];
    a0 = fmaf(act, w.x, a0); a1 = fmaf(act, w.y, a1);
    a2 = fmaf(act, w.z, a2); a3 = fmaf(act, w.w, a3);
  }
  float4 r; r.x = a0; r.y = a1; r.z = a2; r.w = a3;
  *(float4*)&y2[row * 64 + q * 4] = r;
}

__global__ void ro_out_kernel(const float* y2, const float* gf1, const float* bef1,
                              const float* Wt, const float* bt, float* out) {
  __shared__ float aS[64], cS[64], pS[4][64], pQ[4][64];
  int tid = threadIdx.x;
  int c = tid & 63, h = tid >> 6;
  float s = 0, ss = 0;
  for (int rr = h * 64; rr < h * 64 + 64; rr++) {
    float x = y2[rr * 64 + c];
    s += x; ss += x * x;
  }
  pS[h][c] = s; pQ[h][c] = ss;
  __syncthreads();
  if (tid < 64) {
    float S = pS[0][tid] + pS[1][tid] + pS[2][tid] + pS[3][tid];
    float Q = pQ[0][tid] + pQ[1][tid] + pQ[2][tid] + pQ[3][tid];
    float mean = S * (1.0f / 256.0f), var = Q * (1.0f / 256.0f) - mean * mean;
    float av = gf1[tid] * rsqrtf(var + EPS);
    aS[tid] = av; cS[tid] = bef1[tid] - mean * av;
  }
  __syncthreads();
  float acc = bt[0];
  #pragma unroll 4
  for (int cc = 0; cc < 64; cc++)
    acc += siluf_(fmaf(aS[cc], y2[tid * 64 + cc], cS[cc])) * Wt[cc];
  out[tid] = acc;
}

// ---------------- host ----------------

extern "C" void kernel_launch(void* const* d_in, const int* in_sizes, int n_in,
                              void* d_out, int out_size, void* d_ws, size_t ws_size,
                              hipStream_t stream) {
  const float* node_feats = (const float*)d_in[0];
  const float* edge_feats = (const float*)d_in[1];
  const int* src = (const int*)d_in[2];
  const int* dst = (const int*)d_in[3];
  const int* gid = (const int*)d_in[4];
  const float* W_emb = (const float*)d_in[5];
  const float* g_emb = (const float*)d_in[7];
  const float* be_emb = (const float*)d_in[8];
  const float* Wm = (const float*)d_in[9];
  const float* gm = (const float*)d_in[11];
  const float* bem = (const float*)d_in[12];
  const float* Wsc = (const float*)d_in[13];
  const float* gs = (const float*)d_in[15];
  const float* bes = (const float*)d_in[16];
  const float* gn = (const float*)d_in[17];
  const float* ben = (const float*)d_in[18];
  const float* Wf0 = (const float*)d_in[19];
  const float* gf0 = (const float*)d_in[21];
  const float* bef0 = (const float*)d_in[22];
  const float* Wf1 = (const float*)d_in[23];
  const float* gf1 = (const float*)d_in[25];
  const float* bef1 = (const float*)d_in[26];
  const float* Wt = (const float*)d_in[27];
  const float* bt = (const float*)d_in[28];
  float* out = (float*)d_out;

  char* ws = (char*)d_ws;
  size_t off = 0;
  auto alloc = [&](size_t bytes) -> void* {
    void* p = ws + off;
    off = (off + bytes + 511) & ~(size_t)511;
    return p;
  };
  u16* ef_s   = (u16*)alloc((size_t)M_EDGES * 48 * 2);   // padded, bf16
  u32* ybuf   = (u32*)alloc((size_t)M_EDGES * 64 * 4);   // interleaved (mlp|scr) pairs
  u16* Ptop   = (u16*)alloc((size_t)N_NODES * 128 * 2);  // interleaved bf16 tables
  u16* Pmid   = (u16*)alloc((size_t)N_NODES * 128 * 2);
  float* vbuf = (float*)alloc((size_t)N_NODES * 64 * 4);
  float* nbuf = (float*)alloc((size_t)N_NODES * 64 * 4);
  int* row_ptr = (int*)alloc((size_t)(N_NODES + 1) * 4);
  int* nexts   = (int*)alloc((size_t)N_NODES * 4);
  int* eid_s   = (int*)alloc((size_t)M_EDGES * 4);
  int* src_s   = (int*)alloc((size_t)M_EDGES * 4);
  int* dst_s   = (int*)alloc((size_t)M_EDGES * 4);
  int* bsum    = (int*)alloc(256 * 4);
  int* boffs   = (int*)alloc(256 * 4);
  float* stats = (float*)alloc((size_t)80000 * 4);
  (void)ws_size; (void)in_sizes; (void)n_in; (void)out_size;

  // stats region layout (floats); [0, 26880) zeroed each call
  float* emb_p1 = stats + 0;       // [8][64]
  float* emb_p2 = stats + 512;     // [8][64]
  float* ys_p1  = stats + 1024;    // NL x [8][128]
  float* ys_p2  = stats + 4096;    // NL x [8][128]
  float* as_p1  = stats + 7168;    // NL x [8][64]
  float* as_p2  = stats + 8704;    // NL x [8][64]
  float* pcnt   = stats + 10240;   // 256
  float* psum   = stats + 10496;   // 256*64 -> ends 26880
  float* rb1    = stats + 26880;   // 256*128
  float* rb2    = stats + 59648;   // 256*64 -> ends 76032

  // preprocessing
  zero_kernel<<<196, 256, 0, stream>>>(nexts, stats, N_NODES, 26880);
  hist_kernel<<<3125, 256, 0, stream>>>(dst, nexts);
  scanA_kernel<<<196, 256, 0, stream>>>(nexts, bsum);
  scanB_kernel<<<1, 256, 0, stream>>>(bsum, boffs, row_ptr);
  scanC_kernel<<<196, 256, 0, stream>>>(nexts, boffs, row_ptr, nexts);
  scatter_kernel<<<3125, 256, 0, stream>>>(src, dst, nexts, eid_s);
  permute_ef_kernel<<<25000, 256, 0, stream>>>(edge_feats, eid_s, src, dst,
                                               ef_s, src_s, dst_s);

  // embedding (stats fused, 8-slot partials)
  emb_mm_kernel<<<3125, 256, 0, stream>>>(node_feats, W_emb, nbuf, emb_p1, emb_p2);
  finv_ptab_kernel<<<782, 256, 0, stream>>>(nbuf, vbuf, emb_p1, emb_p2, g_emb, be_emb,
                                            Wm, Wsc, Ptop, Pmid, 1.0f / N_NODES, 0);

  for (int l = 0; l < NL; l++) {
    const float* Wm_l = Wm + (size_t)l * 169 * 64;
    const float* Ws_l = Wsc + (size_t)l * 169 * 64;
    edge_mm_kernel<<<512, 256, 0, stream>>>(src_s, dst_s, ef_s, Ptop, Pmid,
                                            Wm_l, Ws_l, ybuf,
                                            ys_p1 + l * 1024, ys_p2 + l * 1024);
    aggregate_kernel<<<3125, 256, 0, stream>>>(ybuf, row_ptr,
                                               ys_p1 + l * 1024, ys_p2 + l * 1024,
                                               gm + l * 64, bem + l * 64,
                                               gs + l * 64, bes + l * 64, nbuf,
                                               as_p1 + l * 512, as_p2 + l * 512);
    if (l < NL - 1) {
      finv_ptab_kernel<<<782, 256, 0, stream>>>(nbuf, vbuf,
                                                as_p1 + l * 512, as_p2 + l * 512,
                                                gn + l * 64, ben + l * 64,
                                                Wm + (size_t)(l + 1) * 169 * 64,
                                                Wsc + (size_t)(l + 1) * 169 * 64,
                                                Ptop, Pmid, 1.0f / N_NODES, 1);
    }
  }

  // fused last-layer node update + pooling, then readout
  node_pool_kernel<<<196, 256, 0, stream>>>(nbuf, vbuf,
                                            as_p1 + (NL - 1) * 512, as_p2 + (NL - 1) * 512,
                                            gn + (NL - 1) * 64, ben + (NL - 1) * 64,
                                            gid, psum, pcnt);
  ro_mm1_kernel<<<32, 256, 0, stream>>>(psum, pcnt, Wf0, rb1);
  ro_mm2_kernel<<<16, 256, 0, stream>>>(rb1, gf0, bef0, Wf1, rb2);
  ro_out_kernel<<<1, 256, 0, stream>>>(rb2, gf1, bef1, Wt, bt, out);
}